// Round 11
// baseline (6337.645 us; speedup 1.0000x reference)
//
#include <hip/hip_runtime.h>

#define SEQ   2048
#define NM    8192        // SEQ*BATCH

typedef __attribute__((ext_vector_type(4))) float f4;
typedef _Float16 f16x8 __attribute__((ext_vector_type(8)));

__device__ __forceinline__ float frcp(float x){ return __builtin_amdgcn_rcpf(x); }
__device__ __forceinline__ float sigm(float x){ return frcp(1.f + __expf(-x)); }
__device__ __forceinline__ float tanhf_(float x){ return 1.f - 2.f*frcp(__expf(2.f*x) + 1.f); }
__device__ __forceinline__ f4 mfma16h(f16x8 a, f16x8 b, f4 c){
  return __builtin_amdgcn_mfma_f32_16x16x32_f16(a, b, c, 0, 0, 0);
}
__device__ __forceinline__ float sel4(f4 v, int u){
  float x = (u & 1) ? v.y : v.x;
  float y = (u & 1) ? v.w : v.z;
  return (u & 2) ? y : x;
}
// LDS-only barrier: scan h coherence needs lgkmcnt(0) only; G prefetch
// global loads stay in flight across the barrier.
__device__ __forceinline__ void barrier_lds_only(){
  asm volatile("s_waitcnt lgkmcnt(0)\n\ts_barrier" ::: "memory");
}

// ---------------------------------------------------------------------------
// Generic tiled GEMM (256 thr): out = A[M,K] @ W[N,K]^T (+bias), epilogues.
// mode 0: plain   mode 2: LSTM-G store [dir][t][b][jj] (b outer, jj inner —
// coalesced), time-reversed for dir1.
// ---------------------------------------------------------------------------
__global__ __launch_bounds__(256) void gemm_k(
    const float* __restrict__ A, int lda,
    const float* __restrict__ W0, const float* __restrict__ W1, int Nhalf,
    const float* __restrict__ b0a, const float* __restrict__ b0b,
    const float* __restrict__ b1a, const float* __restrict__ b1b,
    float* __restrict__ out, int M, int N, int K, int mode)
{
  __shared__ float As[64][17];
  __shared__ float Ws[64][17];
  const int tid = threadIdx.x;
  const int tn = tid & 15, tm = tid >> 4;
  const int n0 = blockIdx.x * 64, m0 = blockIdx.y * 64;
  const int srow = tid >> 2, sk = (tid & 3) * 4;
  float acc[4][4] = {};
  for (int k0 = 0; k0 < K; k0 += 16) {
    const int am = m0 + srow;
    #pragma unroll
    for (int q = 0; q < 4; ++q) {
      int k = k0 + sk + q;
      As[srow][sk + q] = (k < K) ? A[(size_t)am * lda + k] : 0.f;
    }
    const int wn = n0 + srow;
    const float* Wp = W0; int nn = wn;
    if (W1 != nullptr && wn >= Nhalf) { Wp = W1; nn = wn - Nhalf; }
    #pragma unroll
    for (int q = 0; q < 4; ++q) {
      int k = k0 + sk + q;
      Ws[srow][sk + q] = (wn < N && k < K) ? Wp[(size_t)nn * K + k] : 0.f;
    }
    __syncthreads();
    #pragma unroll
    for (int k = 0; k < 16; ++k) {
      float a[4], w[4];
      #pragma unroll
      for (int i = 0; i < 4; ++i) a[i] = As[tm*4+i][k];
      #pragma unroll
      for (int j = 0; j < 4; ++j) w[j] = Ws[tn*4+j][k];
      #pragma unroll
      for (int i = 0; i < 4; ++i)
        #pragma unroll
        for (int j = 0; j < 4; ++j) acc[i][j] += a[i]*w[j];
    }
    __syncthreads();
  }
  #pragma unroll
  for (int i = 0; i < 4; ++i) {
    #pragma unroll
    for (int j = 0; j < 4; ++j) {
      int m = m0 + tm*4 + i, n = n0 + tn*4 + j;
      if (n >= N) continue;
      float bias = 0.f;
      if (n < Nhalf) { if (b0a) bias += b0a[n]; if (b0b) bias += b0b[n]; }
      else { if (b1a) bias += b1a[n - Nhalf]; if (b1b) bias += b1b[n - Nhalf]; }
      float v = acc[i][j] + bias;
      if (mode == 2) {
        int dd = n >> 8, jj = n & 255, t = m >> 2, b = m & 3;
        int tq = dd ? (SEQ - 1 - t) : t;
        out[((size_t)(dd*SEQ + tq) * 4 + b) * 256 + jj] = v;
      } else {
        out[(size_t)m * N + n] = v;
      }
    }
  }
}

// W' = inprojW @ mprojW (512x23, row stride 23), b' = inprojW @ mprojB (512)
__global__ __launch_bounds__(256) void wcomb_k(
    const float* __restrict__ inprojW, const float* __restrict__ mprojW,
    const float* __restrict__ mprojB, float* __restrict__ wc,
    float* __restrict__ bvec)
{
  int idx = blockIdx.x * 256 + threadIdx.x;
  if (idx >= 512 * 24) return;
  int n = idx / 24, c = idx % 24;
  const float* wi = inprojW + (size_t)n * 128;
  float s = 0.f;
  if (c < 23) {
    for (int k = 0; k < 128; ++k) s += wi[k] * mprojW[k*23 + c];
    wc[n*23 + c] = s;
  } else {
    for (int k = 0; k < 128; ++k) s += wi[k] * mprojB[k];
    bvec[n] = s;
  }
}

// yc = (ys + xc*D) * silu(z)   (all [NM,256] contiguous)
__global__ __launch_bounds__(256) void ycomb_k(
    const float* __restrict__ z, const float* __restrict__ ys,
    const float* __restrict__ xc, const float* __restrict__ Dsk,
    float* __restrict__ yc)
{
  int idx = blockIdx.x * 256 + threadIdx.x;
  int d = idx & 255;
  float zz = z[idx];
  yc[idx] = (ys[idx] + xc[idx]*Dsk[d]) * zz * sigm(zz);
}

// ---------------------------------------------------------------------------
// FUSED launch (256 thr): blocks 0-1 = LSTM scan (one dir each, 4 waves —
// R9 base); blocks 2+ = one mamba pipeline stage.
// SCAN (this round's single change): A/B orientation swapped.  A = Whh tile
// (constant, registers; wave w owns gate tiles {4g+w}); B = h replicated 4x
// over the 16 B-cols (col c -> batch c&3).  C layout (col=lane&15=4u+m,
// row=4q+r) then gives lane (l15,q) the gate-g value for (hidcol w*16+4q+r,
// batch m) in reg r of acc g — selecting r=u (replica index) via 2 cndmasks
// yields all 4 gates IN-LANE: the glds LDS round-trip (~140-160 serial
// cyc/step in R9) is gone, activations stay 1-value/lane on all 64 lanes
// (R5 lesson), single lgkm barrier (publish h) remains.
// G layout is [dir][t][b][jj] so the seed loads are f4-contiguous over r.
// Riders: stage 0 xi-gemm; 1 conv+silu; 2 xproj+dt; 3 selective scan.
// ---------------------------------------------------------------------------
#define HROW 80   // padded row stride (f16): 160B = 8 banks mod 32 -> <=2-way
__global__ __launch_bounds__(256, 1) void fused_k(
    int stage,
    const float* __restrict__ G,    // [2][SEQ][4][256]
    const float* __restrict__ Whh,  // [2][256][64] (layer base)
    float* __restrict__ lout,       // [SEQ][4][128]
    const float* __restrict__ rA, int lda,
    const float* __restrict__ rW, const float* __restrict__ rbias,
    float* __restrict__ rout, int ldo, int N, int K,
    const float* __restrict__ dtW, const float* __restrict__ dtB,
    float* __restrict__ dtout,
    const float* __restrict__ mdbc, const float* __restrict__ mdtb,
    const float* __restrict__ mxc, const float* __restrict__ mAlog,
    float* __restrict__ mys)
{
  __shared__ _Float16 hb[2][4][HROW];     // scan: [buf][batch][col]
  __shared__ float As[64][17];            // gemm rider
  __shared__ float Ws[64][17];            // gemm rider
  __shared__ float dtl[64][8];            // stage-2 dt fusion

  const int tid = threadIdx.x;

  if (blockIdx.x < 2) {
    // ---------------- LSTM scan ----------------
    const int dir = blockIdx.x;
    const int w = tid >> 6, lane = tid & 63;   // w in 0..3
    const int l15 = lane & 15, q = lane >> 4;
    const int m = lane & 3, u = (lane >> 2) & 3;
    const int col = w*16 + 4*q + u;            // this lane's hidden unit

    for (int i = tid; i < 2*4*HROW; i += 256) ((_Float16*)hb)[i] = (_Float16)0.f;

    const float* Gd = G + (size_t)dir * SEQ * 1024;
    const float* Wd = Whh + dir * 256 * 64;

    // A fragments (constant): wave w owns gate tiles {4g+w}, g = i,f,g,o.
    // A[row=l15][k=q*8+j] = Whh[(4g+w)*16+l15][k] — same load as R9's W-frag.
    f16x8 ah[4][2];
    #pragma unroll
    for (int g = 0; g < 4; ++g) {
      #pragma unroll
      for (int kt = 0; kt < 2; ++kt) {
        const float* src = Wd + ((g*4 + w)*16 + l15)*64 + kt*32 + q*8;
        #pragma unroll
        for (int e = 0; e < 8; ++e) ah[g][kt][e] = (_Float16)src[e];
      }
    }

    float cc = 0.f;                 // cell state for (batch m, col)
    f4 gp0[4], gp1[4], gp2[4], gp3[4];

    auto loadG = [&](int t, f4* gv) {
      const float* base = Gd + ((size_t)t*4 + m)*256 + w*16 + 4*q;
      #pragma unroll
      for (int g = 0; g < 4; ++g) gv[g] = *(const f4*)(base + g*64);
    };
    loadG(0, gp0); loadG(1, gp1); loadG(2, gp2); loadG(3, gp3);
    __syncthreads();

    auto step = [&](int t, f4* gv) {
      const int p0 = t & 1, p1 = p0 ^ 1;
      // B-frag: B[c=l15][k=q*8+j] = h[batch l15&3][q*8+j] (4x replicated)
      f16x8 bh0 = *(const f16x8*)&hb[p0][m][q*8];
      f16x8 bh1 = *(const f16x8*)&hb[p0][m][q*8 + 32];
      f4 a0 = gv[0], a1 = gv[1], a2 = gv[2], a3 = gv[3];
      a0 = mfma16h(ah[0][0], bh0, a0); a0 = mfma16h(ah[0][1], bh1, a0);
      a1 = mfma16h(ah[1][0], bh0, a1); a1 = mfma16h(ah[1][1], bh1, a1);
      a2 = mfma16h(ah[2][0], bh0, a2); a2 = mfma16h(ah[2][1], bh1, a2);
      a3 = mfma16h(ah[3][0], bh0, a3); a3 = mfma16h(ah[3][1], bh1, a3);
      // in-lane gate select: reg index = replica index u
      float gi = sel4(a0, u);
      float gf = sel4(a1, u);
      float gt = sel4(a2, u);
      float go = sel4(a3, u);
      cc = sigm(gf)*cc + sigm(gi)*tanhf_(gt);
      float hh = sigm(go)*tanhf_(cc);
      hb[p1][m][col] = (_Float16)hh;
      const int to = dir ? (SEQ-1 - t) : t;
      lout[((size_t)to*4 + m)*128 + dir*64 + col] = hh;
      barrier_lds_only();           // single barrier: publish h
    };

    for (int t0 = 0; t0 < SEQ; t0 += 4) {
      step(t0+0, gp0); if (t0+4 < SEQ) loadG(t0+4, gp0);
      step(t0+1, gp1); if (t0+5 < SEQ) loadG(t0+5, gp1);
      step(t0+2, gp2); if (t0+6 < SEQ) loadG(t0+6, gp2);
      step(t0+3, gp3); if (t0+7 < SEQ) loadG(t0+7, gp3);
    }
    return;
  }

  // ---------------- mamba riders (R9 forms, unchanged) ----------------
  const int rb = blockIdx.x - 2;

  if (stage == 1) {       // conv4 + silu: xi [NM,256] -> xc [NM,256]
    int idx = rb*256 + tid;          // < NM*256
    int d = idx & 255, m2 = idx >> 8;
    int t = m2 >> 2, b = m2 & 3;
    float s = rbias[d];
    #pragma unroll
    for (int k = 0; k < 4; ++k) {
      int tt = t - 3 + k;
      if (tt >= 0) s += rA[(size_t)((tt*4 + b) << 8) + d] * rW[d*4 + k];
    }
    rout[idx] = s * sigm(s);
    return;
  }

  if (stage == 3) {       // selective scan, wave per (b,d)
    const int wid = rb*4 + (tid >> 6);
    const int lane = tid & 63;
    const int b = wid >> 8, d = wid & 255;
    const float Av = -__expf(mAlog[d*64 + lane]);
    const float* pB  = mdbc + (size_t)b*136 + 8 + lane;
    const float* pC  = mdbc + (size_t)b*136 + 72 + lane;
    const float* pdt = mdtb + (size_t)b*256 + d;
    const float* px  = mxc  + (size_t)b*256 + d;
    float* py = mys + (size_t)b*256 + d;
    float h = 0.f;
    float Bv = pB[0], Cv = pC[0], dtv = pdt[0], xv = px[0];
    #pragma unroll 2
    for (int t = 0; t < SEQ; ++t) {
      float Bn = 0.f, Cn = 0.f, dtn = 0.f, xn = 0.f;
      if (t + 1 < SEQ) {
        size_t od = (size_t)(t+1) * 544;
        size_t ox = (size_t)(t+1) * 1024;
        Bn = pB[od]; Cn = pC[od]; dtn = pdt[ox]; xn = px[ox];
      }
      float a = __expf(dtv * Av);
      h = a*h + (dtv*xv)*Bv;
      float p = h * Cv;
      #pragma unroll
      for (int mm = 1; mm < 64; mm <<= 1) p += __shfl_xor(p, mm, 64);
      if (lane == 0) py[(size_t)t * 1024] = p;
      Bv = Bn; Cv = Cn; dtv = dtn; xv = xn;
    }
    return;
  }

  // stage 0 / 2: 64x64-tile gemm rider (256 threads).
  // rout = rA @ rW^T (+rbias), rW row stride = K.
  const int ntiles = (N + 63) >> 6;
  const int nt = rb % ntiles, mt = rb / ntiles;
  const int n0 = nt * 64, m0 = mt * 64;
  const int tn = tid & 15, tm = tid >> 4;
  const int srow = tid >> 2, sk = (tid & 3) * 4;
  float acc[4][4] = {};
  for (int k0 = 0; k0 < K; k0 += 16) {
    #pragma unroll
    for (int qq = 0; qq < 4; ++qq) {
      int k = k0 + sk + qq;
      As[srow][sk + qq] = (k < K) ? rA[(size_t)(m0 + srow) * lda + k] : 0.f;
      Ws[srow][sk + qq] = (n0 + srow < N && k < K) ? rW[(size_t)(n0 + srow) * K + k] : 0.f;
    }
    __syncthreads();
    #pragma unroll
    for (int k = 0; k < 16; ++k) {
      float a[4], w[4];
      #pragma unroll
      for (int i = 0; i < 4; ++i) a[i] = As[tm*4+i][k];
      #pragma unroll
      for (int j = 0; j < 4; ++j) w[j] = Ws[tn*4+j][k];
      #pragma unroll
      for (int i = 0; i < 4; ++i)
        #pragma unroll
        for (int j = 0; j < 4; ++j) acc[i][j] += a[i]*w[j];
    }
    __syncthreads();
  }
  #pragma unroll
  for (int i = 0; i < 4; ++i) {
    #pragma unroll
    for (int j = 0; j < 4; ++j) {
      int m2 = m0 + tm*4 + i, n = n0 + tn*4 + j;
      if (n >= N) continue;
      float v = acc[i][j] + (rbias ? rbias[n] : 0.f);
      rout[(size_t)m2 * ldo + n] = v;
      if (stage == 2 && nt == 0 && n < 8) dtl[tm*4+i][n] = v;
    }
  }
  if (stage == 2 && nt == 0) {
    // dt = softplus(dbc[:, :8] @ dtW^T + dtB) for this block's 64 rows
    __syncthreads();
    for (int idx = tid; idx < 64*256; idx += 256) {
      int ml = idx >> 8, d = idx & 255;
      float s = dtB[d];
      #pragma unroll
      for (int r = 0; r < 8; ++r) s += dtl[ml][r] * dtW[d*8 + r];
      s = (s > 15.f) ? s : __logf(1.f + __expf(s));
      dtout[(size_t)(m0 + ml)*256 + d] = s;
    }
  }
}

// final LayerNorm(concat) -> gate -> mix.  One wave per (t,b).
__global__ __launch_bounds__(256) void combine_k(
    const float* __restrict__ lstm, const float* __restrict__ mam,
    const float* __restrict__ lnw, const float* __restrict__ lnb,
    const float* __restrict__ gW, const float* __restrict__ gb,
    float* __restrict__ out)
{
  const int pair = blockIdx.x * 4 + (threadIdx.x >> 6);
  const int lane = threadIdx.x & 63;
  const float2 lv = *(const float2*)(lstm + (size_t)pair*128 + lane*2);
  const float2 mv = *(const float2*)(mam  + (size_t)pair*128 + lane*2);
  float s  = lv.x + lv.y + mv.x + mv.y;
  float sq = lv.x*lv.x + lv.y*lv.y + mv.x*mv.x + mv.y*mv.y;
  #pragma unroll
  for (int mm = 1; mm < 64; mm <<= 1) { s += __shfl_xor(s, mm, 64); sq += __shfl_xor(sq, mm, 64); }
  const float mean = s * (1.f/256.f);
  const float var  = sq * (1.f/256.f) - mean*mean;
  const float inv  = rsqrtf(var + 1e-5f);
  const int c0 = lane*2, c2 = 128 + lane*2;
  float n0 = (lv.x-mean)*inv*lnw[c0]   + lnb[c0];
  float n1 = (lv.y-mean)*inv*lnw[c0+1] + lnb[c0+1];
  float n2 = (mv.x-mean)*inv*lnw[c2]   + lnb[c2];
  float n3 = (mv.y-mean)*inv*lnw[c2+1] + lnb[c2+1];
  float dot = n0*gW[c0] + n1*gW[c0+1] + n2*gW[c2] + n3*gW[c2+1];
  #pragma unroll
  for (int mm = 1; mm < 64; mm <<= 1) dot += __shfl_xor(dot, mm, 64);
  const float gate = sigm(dot + gb[0]);
  float2 o;
  o.x = gate*lv.x + (1.f-gate)*mv.x;
  o.y = gate*lv.y + (1.f-gate)*mv.y;
  *(float2*)(out + (size_t)pair*128 + lane*2) = o;
}

extern "C" void kernel_launch(void* const* d_in, const int* in_sizes, int n_in,
                              void* d_out, int out_size, void* d_ws, size_t ws_size,
                              hipStream_t stream)
{
  const float* x       = (const float*)d_in[0];
  const float* Wih0    = (const float*)d_in[1];
  const float* WihR    = (const float*)d_in[2];
  const float* Whh     = (const float*)d_in[3];
  const float* bih     = (const float*)d_in[4];
  const float* bhh     = (const float*)d_in[5];
  const float* mprojW  = (const float*)d_in[6];
  const float* mprojB  = (const float*)d_in[7];
  const float* inprojW = (const float*)d_in[8];
  const float* convw   = (const float*)d_in[9];
  const float* convb   = (const float*)d_in[10];
  const float* xprojW  = (const float*)d_in[11];
  const float* dtW     = (const float*)d_in[12];
  const float* dtB     = (const float*)d_in[13];
  const float* Alog    = (const float*)d_in[14];
  const float* Dskip   = (const float*)d_in[15];
  const float* outprojW= (const float*)d_in[16];
  const float* lnw     = (const float*)d_in[17];
  const float* lnb     = (const float*)d_in[18];
  const float* gWt     = (const float*)d_in[19];
  const float* gb      = (const float*)d_in[20];

  float* WS = (float*)d_ws;
  const size_t M1 = 1048576;
  // Workspace map (floats) — high water = 1 + 13.25 M1 (R8-proven).
  float* mamba_out = WS;                    // [NM,128]
  float* P     = WS + M1;
  float* G     = P;                         // [2][SEQ][4][256] = 4M1 (lstm); tail: yc
  float* lstmA = P + 4*M1;                  // [NM,128]
  float* lstmB = P + 5*M1;                  // [NM,128]
  float* xi    = P + 6*M1;                  // [NM,256] (F0 out, F1 in)
  float* dtb   = P + 6*M1;                  // alias: [NM,256] (F2 out, F3 in)
  float* zbuf  = P + 6*M1;                  // alias: [NM,256] (tail)
  float* xc    = P + 8*M1;                  // [NM,256] (F1 out; F2, tail in)
  float* dbc   = P + 10*M1;                 // [NM,136] (F2 out, F3 in)
  float* wc    = P + 10*M1 + (size_t)NM*136;// [512][23]
  float* bvec  = wc + 512*23;               // [512]
  float* ysb   = P + 11*M1 + M1/4;          // [NM,256] (F3 out, tail in)
  float* yc    = G;                         // tail: [NM,256] (G dead after F3)
  float* outp  = (float*)d_out;

  dim3 blk(256);

  // pre: fold mproj into in_proj  (W' = inprojW@mprojW, b' = inprojW@mprojB)
  wcomb_k<<<48, blk, 0, stream>>>(inprojW, mprojW, mprojB, wc, bvec);

  // ---- LSTM layers with mamba stages riding the scan launches ----
  const float* lin = x;
  float* louts[4] = {lstmA, lstmB, lstmA, lstmB};
  for (int l = 0; l < 4; ++l) {
    const float* w0; const float* w1; int K;
    if (l == 0) { w0 = Wih0; w1 = Wih0 + 256*23; K = 23; }
    else {
      w0 = WihR + (size_t)((l-1)*2 + 0)*256*128;
      w1 = WihR + (size_t)((l-1)*2 + 1)*256*128;
      K = 128;
    }
    gemm_k<<<dim3(8,128), blk, 0, stream>>>(lin, K, w0, w1, 256,
        bih + (l*2+0)*256, bhh + (l*2+0)*256,
        bih + (l*2+1)*256, bhh + (l*2+1)*256,
        G, NM, 512, K, 2);
    const float* Wl = Whh + (size_t)l*2*256*64;
    if (l == 0) {        // rider: xi = x @ W'[0:256]^T + b'  (4 x 128 tiles)
      fused_k<<<2 + 512, blk, 0, stream>>>(0, G, Wl, louts[l],
          x, 23, wc, bvec, xi, 256, 256, 23,
          nullptr, nullptr, nullptr, nullptr, nullptr, nullptr, nullptr, nullptr);
    } else if (l == 1) { // rider: conv+silu (NM*256 / 256 blocks)
      fused_k<<<2 + 8192, blk, 0, stream>>>(1, G, Wl, louts[l],
          xi, 0, convw, convb, xc, 0, 0, 0,
          nullptr, nullptr, nullptr, nullptr, nullptr, nullptr, nullptr, nullptr);
    } else if (l == 2) { // rider: xproj (3 x 128 tiles) + fused dt
      fused_k<<<2 + 384, blk, 0, stream>>>(2, G, Wl, louts[l],
          xc, 256, xprojW, nullptr, dbc, 136, 136, 256,
          dtW, dtB, dtb, nullptr, nullptr, nullptr, nullptr, nullptr);
    } else {             // rider: mamba selective scan (256 blocks x 4 waves)
      fused_k<<<2 + 256, blk, 0, stream>>>(3, G, Wl, louts[l],
          nullptr, 0, nullptr, nullptr, nullptr, 0, 0, 0,
          nullptr, nullptr, nullptr, dbc, dtb, xc, Alog, ysb);
    }
    lin = louts[l];
  }

  // ---- tail: z-gemm, ycomb, out_proj, gate+mix ----
  gemm_k<<<dim3(4,128), blk, 0, stream>>>(x, 23, wc + 256*23, nullptr, 256,
      bvec + 256, nullptr, nullptr, nullptr, zbuf, NM, 256, 23, 0);
  ycomb_k<<<8192, blk, 0, stream>>>(zbuf, ysb, xc, Dskip, yc);
  gemm_k<<<dim3(2,128), blk, 0, stream>>>(yc, 256, outprojW, nullptr, 128,
      nullptr, nullptr, nullptr, nullptr, mamba_out, NM, 128, 256, 0);
  combine_k<<<2048, blk, 0, stream>>>(lstmB, mamba_out, lnw, lnb, gWt, gb, outp);
}

// Round 12
// 4622.860 us; speedup vs baseline: 1.3709x; 1.3709x over previous
//
#include <hip/hip_runtime.h>

#define SEQ   2048
#define NM    8192        // SEQ*BATCH

typedef __attribute__((ext_vector_type(4))) float f4;
typedef _Float16 f16x8 __attribute__((ext_vector_type(8)));

__device__ __forceinline__ float frcp(float x){ return __builtin_amdgcn_rcpf(x); }
__device__ __forceinline__ float sigm(float x){ return frcp(1.f + __expf(-x)); }
__device__ __forceinline__ float tanhf_(float x){ return 1.f - 2.f*frcp(__expf(2.f*x) + 1.f); }
__device__ __forceinline__ f4 mfma16h(f16x8 a, f16x8 b, f4 c){
  return __builtin_amdgcn_mfma_f32_16x16x32_f16(a, b, c, 0, 0, 0);
}
// LDS-only barrier: scan h/glds coherence needs lgkmcnt(0) only; G prefetch
// global loads stay in flight across the barrier.
__device__ __forceinline__ void barrier_lds_only(){
  asm volatile("s_waitcnt lgkmcnt(0)\n\ts_barrier" ::: "memory");
}

// ---------------------------------------------------------------------------
// Generic tiled GEMM (256 thr): out = A[M,K] @ W[N,K]^T (+bias), epilogues.
// mode 0: plain   mode 2: LSTM-G store [dir][t][j][b], time-reversed for dir1.
// ---------------------------------------------------------------------------
__global__ __launch_bounds__(256) void gemm_k(
    const float* __restrict__ A, int lda,
    const float* __restrict__ W0, const float* __restrict__ W1, int Nhalf,
    const float* __restrict__ b0a, const float* __restrict__ b0b,
    const float* __restrict__ b1a, const float* __restrict__ b1b,
    float* __restrict__ out, int M, int N, int K, int mode)
{
  __shared__ float As[64][17];
  __shared__ float Ws[64][17];
  const int tid = threadIdx.x;
  const int tn = tid & 15, tm = tid >> 4;
  const int n0 = blockIdx.x * 64, m0 = blockIdx.y * 64;
  const int srow = tid >> 2, sk = (tid & 3) * 4;
  float acc[4][4] = {};
  for (int k0 = 0; k0 < K; k0 += 16) {
    const int am = m0 + srow;
    #pragma unroll
    for (int q = 0; q < 4; ++q) {
      int k = k0 + sk + q;
      As[srow][sk + q] = (k < K) ? A[(size_t)am * lda + k] : 0.f;
    }
    const int wn = n0 + srow;
    const float* Wp = W0; int nn = wn;
    if (W1 != nullptr && wn >= Nhalf) { Wp = W1; nn = wn - Nhalf; }
    #pragma unroll
    for (int q = 0; q < 4; ++q) {
      int k = k0 + sk + q;
      Ws[srow][sk + q] = (wn < N && k < K) ? Wp[(size_t)nn * K + k] : 0.f;
    }
    __syncthreads();
    #pragma unroll
    for (int k = 0; k < 16; ++k) {
      float a[4], w[4];
      #pragma unroll
      for (int i = 0; i < 4; ++i) a[i] = As[tm*4+i][k];
      #pragma unroll
      for (int j = 0; j < 4; ++j) w[j] = Ws[tn*4+j][k];
      #pragma unroll
      for (int i = 0; i < 4; ++i)
        #pragma unroll
        for (int j = 0; j < 4; ++j) acc[i][j] += a[i]*w[j];
    }
    __syncthreads();
  }
  #pragma unroll
  for (int i = 0; i < 4; ++i) {
    #pragma unroll
    for (int j = 0; j < 4; ++j) {
      int m = m0 + tm*4 + i, n = n0 + tn*4 + j;
      if (n >= N) continue;
      float bias = 0.f;
      if (n < Nhalf) { if (b0a) bias += b0a[n]; if (b0b) bias += b0b[n]; }
      else { if (b1a) bias += b1a[n - Nhalf]; if (b1b) bias += b1b[n - Nhalf]; }
      float v = acc[i][j] + bias;
      if (mode == 2) {
        int dd = n >> 8, jj = n & 255, t = m >> 2, b = m & 3;
        int tq = dd ? (SEQ - 1 - t) : t;
        out[((size_t)(dd*SEQ + tq) * 256 + jj) * 4 + b] = v;
      } else {
        out[(size_t)m * N + n] = v;
      }
    }
  }
}

// W' = inprojW @ mprojW (512x23, row stride 23), b' = inprojW @ mprojB (512)
__global__ __launch_bounds__(256) void wcomb_k(
    const float* __restrict__ inprojW, const float* __restrict__ mprojW,
    const float* __restrict__ mprojB, float* __restrict__ wc,
    float* __restrict__ bvec)
{
  int idx = blockIdx.x * 256 + threadIdx.x;
  if (idx >= 512 * 24) return;
  int n = idx / 24, c = idx % 24;
  const float* wi = inprojW + (size_t)n * 128;
  float s = 0.f;
  if (c < 23) {
    for (int k = 0; k < 128; ++k) s += wi[k] * mprojW[k*23 + c];
    wc[n*23 + c] = s;
  } else {
    for (int k = 0; k < 128; ++k) s += wi[k] * mprojB[k];
    bvec[n] = s;
  }
}

// yc = (ys + xc*D) * silu(z)   (all [NM,256] contiguous)
__global__ __launch_bounds__(256) void ycomb_k(
    const float* __restrict__ z, const float* __restrict__ ys,
    const float* __restrict__ xc, const float* __restrict__ Dsk,
    float* __restrict__ yc)
{
  int idx = blockIdx.x * 256 + threadIdx.x;
  int d = idx & 255;
  float zz = z[idx];
  yc[idx] = (ys[idx] + xc[idx]*Dsk[d]) * zz * sigm(zz);
}

// ---------------------------------------------------------------------------
// FUSED launch (256 thr): blocks 0-1 = LSTM scan (one dir each, 4 waves —
// the R9 structure, proven best); blocks 2+ = one mamba pipeline stage.
// SCAN: wave w owns gate tiles {w, w+4, w+8, w+12} (all 4 gates for hid cols
// 16w..16w+15); single-pass f16 MFMA (8 MFMAs/wave, 2-deep chains);
// intra-wave glds gate redistribution (write lane<16 -> read all lanes,
// compiler lgkmcnt only); activations 1 value/lane on all 64 lanes; ONE lgkm
// barrier per step (publish h).
// THIS ROUND'S single change vs R9: HROW 80 -> 72.  160B row stride = 8 banks
// mod 32 put lanes {l15, l15+4, l15+8, l15+12} of each b128 h-read on the
// same bank quad (4-way conflict, SQ_LDS_BANK_CONFLICT = 64/step = 131072);
// 144B = 4 banks mod 32 makes the worst case 2-way, which is free (m136).
// Riders: stage 0 xi-gemm; 1 conv+silu; 2 xproj+dt; 3 selective scan.
// ---------------------------------------------------------------------------
#define HROW 72   // padded row stride (f16): 144B = 4 banks mod 32 -> <=2-way
__global__ __launch_bounds__(256, 1) void fused_k(
    int stage,
    const float* __restrict__ G,    // [2][SEQ][256][4]
    const float* __restrict__ Whh,  // [2][256][64] (layer base)
    float* __restrict__ lout,       // [SEQ][4][128]
    const float* __restrict__ rA, int lda,
    const float* __restrict__ rW, const float* __restrict__ rbias,
    float* __restrict__ rout, int ldo, int N, int K,
    const float* __restrict__ dtW, const float* __restrict__ dtB,
    float* __restrict__ dtout,
    const float* __restrict__ mdbc, const float* __restrict__ mdtb,
    const float* __restrict__ mxc, const float* __restrict__ mAlog,
    float* __restrict__ mys)
{
  __shared__ _Float16 hb[2][16][HROW];    // scan: [buf][m=batch][k=col]
  __shared__ float glds[4][4][16][4];     // scan: [wave][gate][col][batch]
  __shared__ float As[64][17];            // gemm rider
  __shared__ float Ws[64][17];            // gemm rider
  __shared__ float dtl[64][8];            // stage-2 dt fusion

  const int tid = threadIdx.x;

  if (blockIdx.x < 2) {
    // ---------------- LSTM scan ----------------
    const int dir = blockIdx.x;
    const int w = tid >> 6, lane = tid & 63;   // w in 0..3
    const int l15 = lane & 15, q = lane >> 4;

    for (int i = tid; i < 2*16*HROW; i += 256) ((_Float16*)hb)[i] = (_Float16)0.f;

    const float* Gd = G + (size_t)dir * SEQ * 1024;
    const float* Wd = Whh + dir * 256 * 64;

    // B fragments: wave w owns gate tiles {4g+w}, g=0..3 (gate i,f,g,o)
    f16x8 bh[4][2];
    #pragma unroll
    for (int g = 0; g < 4; ++g) {
      const int j = (g*4 + w)*16 + l15;
      #pragma unroll
      for (int kt = 0; kt < 2; ++kt) {
        const float* src = Wd + j*64 + kt*32 + q*8;
        #pragma unroll
        for (int e = 0; e < 8; ++e) bh[g][kt][e] = (_Float16)src[e];
      }
    }

    float cc = 0.f;                 // cell state: lane = (batch q, col 16w+l15)
    f4 gp0[4], gp1[4], gp2[4], gp3[4];

    auto loadG = [&](int t, f4* gv) {
      #pragma unroll
      for (int g = 0; g < 4; ++g) {
        const int j = (g*4 + w)*16 + l15;
        gv[g] = *(const f4*)(Gd + ((size_t)t * 256 + j) * 4);
      }
    };
    loadG(0, gp0); loadG(1, gp1); loadG(2, gp2); loadG(3, gp3);
    __syncthreads();

    auto step = [&](int t, f4* gv) {
      const int p0 = t & 1, p1 = p0 ^ 1;
      f16x8 ah0 = *(const f16x8*)&hb[p0][l15][q*8];
      f16x8 ah1 = *(const f16x8*)&hb[p0][l15][q*8 + 32];
      f4 a0 = gv[0], a1 = gv[1], a2 = gv[2], a3 = gv[3];
      a0 = mfma16h(ah0, bh[0][0], a0); a0 = mfma16h(ah1, bh[0][1], a0);
      a1 = mfma16h(ah0, bh[1][0], a1); a1 = mfma16h(ah1, bh[1][1], a1);
      a2 = mfma16h(ah0, bh[2][0], a2); a2 = mfma16h(ah1, bh[2][1], a2);
      a3 = mfma16h(ah0, bh[3][0], a3); a3 = mfma16h(ah1, bh[3][1], a3);
      if (lane < 16) {
        *(f4*)&glds[w][0][l15][0] = a0;
        *(f4*)&glds[w][1][l15][0] = a1;
        *(f4*)&glds[w][2][l15][0] = a2;
        *(f4*)&glds[w][3][l15][0] = a3;
      }
      // intra-wave write->read: compiler lgkmcnt, no barrier (R2-proven)
      float gi = glds[w][0][l15][q];
      float gf = glds[w][1][l15][q];
      float gt = glds[w][2][l15][q];
      float go = glds[w][3][l15][q];
      cc = sigm(gf)*cc + sigm(gi)*tanhf_(gt);
      float hh = sigm(go)*tanhf_(cc);
      hb[p1][q][w*16 + l15] = (_Float16)hh;
      const int to = dir ? (SEQ-1 - t) : t;
      lout[((size_t)to*4 + q)*128 + dir*64 + w*16 + l15] = hh;
      barrier_lds_only();           // single barrier: publish h
    };

    for (int t0 = 0; t0 < SEQ; t0 += 4) {
      step(t0+0, gp0); if (t0+4 < SEQ) loadG(t0+4, gp0);
      step(t0+1, gp1); if (t0+5 < SEQ) loadG(t0+5, gp1);
      step(t0+2, gp2); if (t0+6 < SEQ) loadG(t0+6, gp2);
      step(t0+3, gp3); if (t0+7 < SEQ) loadG(t0+7, gp3);
    }
    return;
  }

  // ---------------- mamba riders ----------------
  const int rb = blockIdx.x - 2;

  if (stage == 1) {       // conv4 + silu: xi [NM,256] -> xc [NM,256]
    int idx = rb*256 + tid;          // < NM*256
    int d = idx & 255, m2 = idx >> 8;
    int t = m2 >> 2, b = m2 & 3;
    float s = rbias[d];
    #pragma unroll
    for (int k = 0; k < 4; ++k) {
      int tt = t - 3 + k;
      if (tt >= 0) s += rA[(size_t)((tt*4 + b) << 8) + d] * rW[d*4 + k];
    }
    rout[idx] = s * sigm(s);
    return;
  }

  if (stage == 3) {       // selective scan, wave per (b,d)
    const int wid = rb*4 + (tid >> 6);
    const int lane = tid & 63;
    const int b = wid >> 8, d = wid & 255;
    const float Av = -__expf(mAlog[d*64 + lane]);
    const float* pB  = mdbc + (size_t)b*136 + 8 + lane;
    const float* pC  = mdbc + (size_t)b*136 + 72 + lane;
    const float* pdt = mdtb + (size_t)b*256 + d;
    const float* px  = mxc  + (size_t)b*256 + d;
    float* py = mys + (size_t)b*256 + d;
    float h = 0.f;
    float Bv = pB[0], Cv = pC[0], dtv = pdt[0], xv = px[0];
    #pragma unroll 2
    for (int t = 0; t < SEQ; ++t) {
      float Bn = 0.f, Cn = 0.f, dtn = 0.f, xn = 0.f;
      if (t + 1 < SEQ) {
        size_t od = (size_t)(t+1) * 544;
        size_t ox = (size_t)(t+1) * 1024;
        Bn = pB[od]; Cn = pC[od]; dtn = pdt[ox]; xn = px[ox];
      }
      float a = __expf(dtv * Av);
      h = a*h + (dtv*xv)*Bv;
      float p = h * Cv;
      #pragma unroll
      for (int mm = 1; mm < 64; mm <<= 1) p += __shfl_xor(p, mm, 64);
      if (lane == 0) py[(size_t)t * 1024] = p;
      Bv = Bn; Cv = Cn; dtv = dtn; xv = xn;
    }
    return;
  }

  // stage 0 / 2: 64x64-tile gemm rider (256 threads).
  // rout = rA @ rW^T (+rbias), rW row stride = K.
  const int ntiles = (N + 63) >> 6;
  const int nt = rb % ntiles, mt = rb / ntiles;
  const int n0 = nt * 64, m0 = mt * 64;
  const int tn = tid & 15, tm = tid >> 4;
  const int srow = tid >> 2, sk = (tid & 3) * 4;
  float acc[4][4] = {};
  for (int k0 = 0; k0 < K; k0 += 16) {
    #pragma unroll
    for (int qq = 0; qq < 4; ++qq) {
      int k = k0 + sk + qq;
      As[srow][sk + qq] = (k < K) ? rA[(size_t)(m0 + srow) * lda + k] : 0.f;
      Ws[srow][sk + qq] = (n0 + srow < N && k < K) ? rW[(size_t)(n0 + srow) * K + k] : 0.f;
    }
    __syncthreads();
    #pragma unroll
    for (int k = 0; k < 16; ++k) {
      float a[4], w[4];
      #pragma unroll
      for (int i = 0; i < 4; ++i) a[i] = As[tm*4+i][k];
      #pragma unroll
      for (int j = 0; j < 4; ++j) w[j] = Ws[tn*4+j][k];
      #pragma unroll
      for (int i = 0; i < 4; ++i)
        #pragma unroll
        for (int j = 0; j < 4; ++j) acc[i][j] += a[i]*w[j];
    }
    __syncthreads();
  }
  #pragma unroll
  for (int i = 0; i < 4; ++i) {
    #pragma unroll
    for (int j = 0; j < 4; ++j) {
      int m2 = m0 + tm*4 + i, n = n0 + tn*4 + j;
      if (n >= N) continue;
      float v = acc[i][j] + (rbias ? rbias[n] : 0.f);
      rout[(size_t)m2 * ldo + n] = v;
      if (stage == 2 && nt == 0 && n < 8) dtl[tm*4+i][n] = v;
    }
  }
  if (stage == 2 && nt == 0) {
    // dt = softplus(dbc[:, :8] @ dtW^T + dtB) for this block's 64 rows
    __syncthreads();
    for (int idx = tid; idx < 64*256; idx += 256) {
      int ml = idx >> 8, d = idx & 255;
      float s = dtB[d];
      #pragma unroll
      for (int r = 0; r < 8; ++r) s += dtl[ml][r] * dtW[d*8 + r];
      s = (s > 15.f) ? s : __logf(1.f + __expf(s));
      dtout[(size_t)(m0 + ml)*256 + d] = s;
    }
  }
}

// final LayerNorm(concat) -> gate -> mix.  One wave per (t,b).
__global__ __launch_bounds__(256) void combine_k(
    const float* __restrict__ lstm, const float* __restrict__ mam,
    const float* __restrict__ lnw, const float* __restrict__ lnb,
    const float* __restrict__ gW, const float* __restrict__ gb,
    float* __restrict__ out)
{
  const int pair = blockIdx.x * 4 + (threadIdx.x >> 6);
  const int lane = threadIdx.x & 63;
  const float2 lv = *(const float2*)(lstm + (size_t)pair*128 + lane*2);
  const float2 mv = *(const float2*)(mam  + (size_t)pair*128 + lane*2);
  float s  = lv.x + lv.y + mv.x + mv.y;
  float sq = lv.x*lv.x + lv.y*lv.y + mv.x*mv.x + mv.y*mv.y;
  #pragma unroll
  for (int mm = 1; mm < 64; mm <<= 1) { s += __shfl_xor(s, mm, 64); sq += __shfl_xor(sq, mm, 64); }
  const float mean = s * (1.f/256.f);
  const float var  = sq * (1.f/256.f) - mean*mean;
  const float inv  = rsqrtf(var + 1e-5f);
  const int c0 = lane*2, c2 = 128 + lane*2;
  float n0 = (lv.x-mean)*inv*lnw[c0]   + lnb[c0];
  float n1 = (lv.y-mean)*inv*lnw[c0+1] + lnb[c0+1];
  float n2 = (mv.x-mean)*inv*lnw[c2]   + lnb[c2];
  float n3 = (mv.y-mean)*inv*lnw[c2+1] + lnb[c2+1];
  float dot = n0*gW[c0] + n1*gW[c0+1] + n2*gW[c2] + n3*gW[c2+1];
  #pragma unroll
  for (int mm = 1; mm < 64; mm <<= 1) dot += __shfl_xor(dot, mm, 64);
  const float gate = sigm(dot + gb[0]);
  float2 o;
  o.x = gate*lv.x + (1.f-gate)*mv.x;
  o.y = gate*lv.y + (1.f-gate)*mv.y;
  *(float2*)(out + (size_t)pair*128 + lane*2) = o;
}

extern "C" void kernel_launch(void* const* d_in, const int* in_sizes, int n_in,
                              void* d_out, int out_size, void* d_ws, size_t ws_size,
                              hipStream_t stream)
{
  const float* x       = (const float*)d_in[0];
  const float* Wih0    = (const float*)d_in[1];
  const float* WihR    = (const float*)d_in[2];
  const float* Whh     = (const float*)d_in[3];
  const float* bih     = (const float*)d_in[4];
  const float* bhh     = (const float*)d_in[5];
  const float* mprojW  = (const float*)d_in[6];
  const float* mprojB  = (const float*)d_in[7];
  const float* inprojW = (const float*)d_in[8];
  const float* convw   = (const float*)d_in[9];
  const float* convb   = (const float*)d_in[10];
  const float* xprojW  = (const float*)d_in[11];
  const float* dtW     = (const float*)d_in[12];
  const float* dtB     = (const float*)d_in[13];
  const float* Alog    = (const float*)d_in[14];
  const float* Dskip   = (const float*)d_in[15];
  const float* outprojW= (const float*)d_in[16];
  const float* lnw     = (const float*)d_in[17];
  const float* lnb     = (const float*)d_in[18];
  const float* gWt     = (const float*)d_in[19];
  const float* gb      = (const float*)d_in[20];

  float* WS = (float*)d_ws;
  const size_t M1 = 1048576;
  // Workspace map (floats) — high water = 1 + 13.25 M1 (R8-proven).
  float* mamba_out = WS;                    // [NM,128]
  float* P     = WS + M1;
  float* G     = P;                         // [2][SEQ][256][4] = 4M1 (lstm); tail: yc
  float* lstmA = P + 4*M1;                  // [NM,128]
  float* lstmB = P + 5*M1;                  // [NM,128]
  float* xi    = P + 6*M1;                  // [NM,256] (F0 out, F1 in)
  float* dtb   = P + 6*M1;                  // alias: [NM,256] (F2 out, F3 in)
  float* zbuf  = P + 6*M1;                  // alias: [NM,256] (tail)
  float* xc    = P + 8*M1;                  // [NM,256] (F1 out; F2, tail in)
  float* dbc   = P + 10*M1;                 // [NM,136] (F2 out, F3 in)
  float* wc    = P + 10*M1 + (size_t)NM*136;// [512][23]
  float* bvec  = wc + 512*23;               // [512]
  float* ysb   = P + 11*M1 + M1/4;          // [NM,256] (F3 out, tail in)
  float* yc    = G;                         // tail: [NM,256] (G dead after F3)
  float* outp  = (float*)d_out;

  dim3 blk(256);

  // pre: fold mproj into in_proj  (W' = inprojW@mprojW, b' = inprojW@mprojB)
  wcomb_k<<<48, blk, 0, stream>>>(inprojW, mprojW, mprojB, wc, bvec);

  // ---- LSTM layers with mamba stages riding the scan launches ----
  const float* lin = x;
  float* louts[4] = {lstmA, lstmB, lstmA, lstmB};
  for (int l = 0; l < 4; ++l) {
    const float* w0; const float* w1; int K;
    if (l == 0) { w0 = Wih0; w1 = Wih0 + 256*23; K = 23; }
    else {
      w0 = WihR + (size_t)((l-1)*2 + 0)*256*128;
      w1 = WihR + (size_t)((l-1)*2 + 1)*256*128;
      K = 128;
    }
    gemm_k<<<dim3(8,128), blk, 0, stream>>>(lin, K, w0, w1, 256,
        bih + (l*2+0)*256, bhh + (l*2+0)*256,
        bih + (l*2+1)*256, bhh + (l*2+1)*256,
        G, NM, 512, K, 2);
    const float* Wl = Whh + (size_t)l*2*256*64;
    if (l == 0) {        // rider: xi = x @ W'[0:256]^T + b'  (4 x 128 tiles)
      fused_k<<<2 + 512, blk, 0, stream>>>(0, G, Wl, louts[l],
          x, 23, wc, bvec, xi, 256, 256, 23,
          nullptr, nullptr, nullptr, nullptr, nullptr, nullptr, nullptr, nullptr);
    } else if (l == 1) { // rider: conv+silu (NM*256 / 256 blocks)
      fused_k<<<2 + 8192, blk, 0, stream>>>(1, G, Wl, louts[l],
          xi, 0, convw, convb, xc, 0, 0, 0,
          nullptr, nullptr, nullptr, nullptr, nullptr, nullptr, nullptr, nullptr);
    } else if (l == 2) { // rider: xproj (3 x 128 tiles) + fused dt
      fused_k<<<2 + 384, blk, 0, stream>>>(2, G, Wl, louts[l],
          xc, 256, xprojW, nullptr, dbc, 136, 136, 256,
          dtW, dtB, dtb, nullptr, nullptr, nullptr, nullptr, nullptr);
    } else {             // rider: mamba selective scan (256 blocks x 4 waves)
      fused_k<<<2 + 256, blk, 0, stream>>>(3, G, Wl, louts[l],
          nullptr, 0, nullptr, nullptr, nullptr, 0, 0, 0,
          nullptr, nullptr, nullptr, dbc, dtb, xc, Alog, ysb);
    }
    lin = louts[l];
  }

  // ---- tail: z-gemm, ycomb, out_proj, gate+mix ----
  gemm_k<<<dim3(4,128), blk, 0, stream>>>(x, 23, wc + 256*23, nullptr, 256,
      bvec + 256, nullptr, nullptr, nullptr, zbuf, NM, 256, 23, 0);
  ycomb_k<<<8192, blk, 0, stream>>>(zbuf, ysb, xc, Dskip, yc);
  gemm_k<<<dim3(2,128), blk, 0, stream>>>(yc, 256, outprojW, nullptr, 128,
      nullptr, nullptr, nullptr, nullptr, mamba_out, NM, 128, 256, 0);
  combine_k<<<2048, blk, 0, stream>>>(lstmB, mamba_out, lnw, lnb, gWt, gb, outp);
}

// Round 13
// 4599.344 us; speedup vs baseline: 1.3779x; 1.0051x over previous
//
#include <hip/hip_runtime.h>

#define SEQ   2048
#define NM    8192        // SEQ*BATCH

typedef __attribute__((ext_vector_type(4))) float f4;
typedef _Float16 f16x8 __attribute__((ext_vector_type(8)));

__device__ __forceinline__ float frcp(float x){ return __builtin_amdgcn_rcpf(x); }
__device__ __forceinline__ float sigm(float x){ return frcp(1.f + __expf(-x)); }
__device__ __forceinline__ float tanhf_(float x){ return 1.f - 2.f*frcp(__expf(2.f*x) + 1.f); }
__device__ __forceinline__ f4 mfma16h(f16x8 a, f16x8 b, f4 c){
  return __builtin_amdgcn_mfma_f32_16x16x32_f16(a, b, c, 0, 0, 0);
}
// LDS-only barrier: scan h/glds coherence needs lgkmcnt(0) only; G prefetch
// global loads stay in flight across the barrier.
__device__ __forceinline__ void barrier_lds_only(){
  asm volatile("s_waitcnt lgkmcnt(0)\n\ts_barrier" ::: "memory");
}

// ---------------------------------------------------------------------------
// Generic tiled GEMM (256 thr): out = A[M,K] @ W[N,K]^T (+bias), epilogues.
// mode 0: plain   mode 2: LSTM-G store [dir][t][j][b], time-reversed for dir1.
// ---------------------------------------------------------------------------
__global__ __launch_bounds__(256) void gemm_k(
    const float* __restrict__ A, int lda,
    const float* __restrict__ W0, const float* __restrict__ W1, int Nhalf,
    const float* __restrict__ b0a, const float* __restrict__ b0b,
    const float* __restrict__ b1a, const float* __restrict__ b1b,
    float* __restrict__ out, int M, int N, int K, int mode)
{
  __shared__ float As[64][17];
  __shared__ float Ws[64][17];
  const int tid = threadIdx.x;
  const int tn = tid & 15, tm = tid >> 4;
  const int n0 = blockIdx.x * 64, m0 = blockIdx.y * 64;
  const int srow = tid >> 2, sk = (tid & 3) * 4;
  float acc[4][4] = {};
  for (int k0 = 0; k0 < K; k0 += 16) {
    const int am = m0 + srow;
    #pragma unroll
    for (int q = 0; q < 4; ++q) {
      int k = k0 + sk + q;
      As[srow][sk + q] = (k < K) ? A[(size_t)am * lda + k] : 0.f;
    }
    const int wn = n0 + srow;
    const float* Wp = W0; int nn = wn;
    if (W1 != nullptr && wn >= Nhalf) { Wp = W1; nn = wn - Nhalf; }
    #pragma unroll
    for (int q = 0; q < 4; ++q) {
      int k = k0 + sk + q;
      Ws[srow][sk + q] = (wn < N && k < K) ? Wp[(size_t)nn * K + k] : 0.f;
    }
    __syncthreads();
    #pragma unroll
    for (int k = 0; k < 16; ++k) {
      float a[4], w[4];
      #pragma unroll
      for (int i = 0; i < 4; ++i) a[i] = As[tm*4+i][k];
      #pragma unroll
      for (int j = 0; j < 4; ++j) w[j] = Ws[tn*4+j][k];
      #pragma unroll
      for (int i = 0; i < 4; ++i)
        #pragma unroll
        for (int j = 0; j < 4; ++j) acc[i][j] += a[i]*w[j];
    }
    __syncthreads();
  }
  #pragma unroll
  for (int i = 0; i < 4; ++i) {
    #pragma unroll
    for (int j = 0; j < 4; ++j) {
      int m = m0 + tm*4 + i, n = n0 + tn*4 + j;
      if (n >= N) continue;
      float bias = 0.f;
      if (n < Nhalf) { if (b0a) bias += b0a[n]; if (b0b) bias += b0b[n]; }
      else { if (b1a) bias += b1a[n - Nhalf]; if (b1b) bias += b1b[n - Nhalf]; }
      float v = acc[i][j] + bias;
      if (mode == 2) {
        int dd = n >> 8, jj = n & 255, t = m >> 2, b = m & 3;
        int tq = dd ? (SEQ - 1 - t) : t;
        out[((size_t)(dd*SEQ + tq) * 256 + jj) * 4 + b] = v;
      } else {
        out[(size_t)m * N + n] = v;
      }
    }
  }
}

// W' = inprojW @ mprojW (512x23, row stride 23), b' = inprojW @ mprojB (512)
__global__ __launch_bounds__(256) void wcomb_k(
    const float* __restrict__ inprojW, const float* __restrict__ mprojW,
    const float* __restrict__ mprojB, float* __restrict__ wc,
    float* __restrict__ bvec)
{
  int idx = blockIdx.x * 256 + threadIdx.x;
  if (idx >= 512 * 24) return;
  int n = idx / 24, c = idx % 24;
  const float* wi = inprojW + (size_t)n * 128;
  float s = 0.f;
  if (c < 23) {
    for (int k = 0; k < 128; ++k) s += wi[k] * mprojW[k*23 + c];
    wc[n*23 + c] = s;
  } else {
    for (int k = 0; k < 128; ++k) s += wi[k] * mprojB[k];
    bvec[n] = s;
  }
}

// out = yc @ Wp[128,256]^T with yc computed inline: yc = (ys + xc*D)*silu(z).
// Fuses the old ycomb_k into the out_proj GEMM's A-staging (kills one kernel
// launch + the 16 MB yc round-trip).
__global__ __launch_bounds__(256) void moutproj_k(
    const float* __restrict__ z, const float* __restrict__ ys,
    const float* __restrict__ xc, const float* __restrict__ Dsk,
    const float* __restrict__ Wp, float* __restrict__ out)
{
  __shared__ float As[64][17];
  __shared__ float Ws[64][17];
  const int tid = threadIdx.x;
  const int tn = tid & 15, tm = tid >> 4;
  const int n0 = blockIdx.x * 64, m0 = blockIdx.y * 64;
  const int srow = tid >> 2, sk = (tid & 3) * 4;
  float acc[4][4] = {};
  for (int k0 = 0; k0 < 256; k0 += 16) {
    #pragma unroll
    for (int q = 0; q < 4; ++q) {
      int k = k0 + sk + q;
      size_t idx = (size_t)(m0 + srow) * 256 + k;
      float zz = z[idx];
      As[srow][sk + q] = (ys[idx] + xc[idx]*Dsk[k]) * zz * sigm(zz);
      Ws[srow][sk + q] = Wp[(size_t)(n0 + srow) * 256 + k];
    }
    __syncthreads();
    #pragma unroll
    for (int k = 0; k < 16; ++k) {
      float a[4], w[4];
      #pragma unroll
      for (int i = 0; i < 4; ++i) a[i] = As[tm*4+i][k];
      #pragma unroll
      for (int j = 0; j < 4; ++j) w[j] = Ws[tn*4+j][k];
      #pragma unroll
      for (int i = 0; i < 4; ++i)
        #pragma unroll
        for (int j = 0; j < 4; ++j) acc[i][j] += a[i]*w[j];
    }
    __syncthreads();
  }
  #pragma unroll
  for (int i = 0; i < 4; ++i)
    #pragma unroll
    for (int j = 0; j < 4; ++j)
      out[(size_t)(m0 + tm*4 + i) * 128 + n0 + tn*4 + j] = acc[i][j];
}

// ---------------------------------------------------------------------------
// FUSED launch (256 thr): blocks 0-1 = LSTM scan (one dir each, 4 waves —
// the R9 structure, proven best); blocks 2+ = one mamba pipeline stage.
// SCAN: wave w owns gate tiles {w, w+4, w+8, w+12}; single-pass f16 MFMA
// (8 MFMAs/wave, 2-deep chains); intra-wave glds gate redistribution;
// activations 1 value/lane on all 64 lanes; ONE lgkm barrier per step.
// Riders: stage 0 xi-gemm (+ optional z-gemm blocks rb>=512, using the
// dtW/dtB/dtout params as weight/bias/out — z depends only on x and wc so it
// hides under the l=0 scan); 1 conv+silu; 2 xproj+dt; 3 selective scan.
// ---------------------------------------------------------------------------
#define HROW 72   // padded row stride (f16)
__global__ __launch_bounds__(256, 1) void fused_k(
    int stage,
    const float* __restrict__ G,    // [2][SEQ][256][4]
    const float* __restrict__ Whh,  // [2][256][64] (layer base)
    float* __restrict__ lout,       // [SEQ][4][128]
    const float* __restrict__ rA, int lda,
    const float* __restrict__ rW, const float* __restrict__ rbias,
    float* __restrict__ rout, int ldo, int N, int K,
    const float* __restrict__ dtW, const float* __restrict__ dtB,
    float* __restrict__ dtout,
    const float* __restrict__ mdbc, const float* __restrict__ mdtb,
    const float* __restrict__ mxc, const float* __restrict__ mAlog,
    float* __restrict__ mys)
{
  __shared__ _Float16 hb[2][16][HROW];    // scan: [buf][m=batch][k=col]
  __shared__ float glds[4][4][16][4];     // scan: [wave][gate][col][batch]
  __shared__ float As[64][17];            // gemm rider
  __shared__ float Ws[64][17];            // gemm rider
  __shared__ float dtl[64][8];            // stage-2 dt fusion

  const int tid = threadIdx.x;

  if (blockIdx.x < 2) {
    // ---------------- LSTM scan ----------------
    const int dir = blockIdx.x;
    const int w = tid >> 6, lane = tid & 63;   // w in 0..3
    const int l15 = lane & 15, q = lane >> 4;

    for (int i = tid; i < 2*16*HROW; i += 256) ((_Float16*)hb)[i] = (_Float16)0.f;

    const float* Gd = G + (size_t)dir * SEQ * 1024;
    const float* Wd = Whh + dir * 256 * 64;

    // B fragments: wave w owns gate tiles {4g+w}, g=0..3 (gate i,f,g,o)
    f16x8 bh[4][2];
    #pragma unroll
    for (int g = 0; g < 4; ++g) {
      const int j = (g*4 + w)*16 + l15;
      #pragma unroll
      for (int kt = 0; kt < 2; ++kt) {
        const float* src = Wd + j*64 + kt*32 + q*8;
        #pragma unroll
        for (int e = 0; e < 8; ++e) bh[g][kt][e] = (_Float16)src[e];
      }
    }

    float cc = 0.f;                 // cell state: lane = (batch q, col 16w+l15)
    f4 gp0[4], gp1[4], gp2[4], gp3[4];

    auto loadG = [&](int t, f4* gv) {
      #pragma unroll
      for (int g = 0; g < 4; ++g) {
        const int j = (g*4 + w)*16 + l15;
        gv[g] = *(const f4*)(Gd + ((size_t)t * 256 + j) * 4);
      }
    };
    loadG(0, gp0); loadG(1, gp1); loadG(2, gp2); loadG(3, gp3);
    __syncthreads();

    auto step = [&](int t, f4* gv) {
      const int p0 = t & 1, p1 = p0 ^ 1;
      f16x8 ah0 = *(const f16x8*)&hb[p0][l15][q*8];
      f16x8 ah1 = *(const f16x8*)&hb[p0][l15][q*8 + 32];
      f4 a0 = gv[0], a1 = gv[1], a2 = gv[2], a3 = gv[3];
      a0 = mfma16h(ah0, bh[0][0], a0); a0 = mfma16h(ah1, bh[0][1], a0);
      a1 = mfma16h(ah0, bh[1][0], a1); a1 = mfma16h(ah1, bh[1][1], a1);
      a2 = mfma16h(ah0, bh[2][0], a2); a2 = mfma16h(ah1, bh[2][1], a2);
      a3 = mfma16h(ah0, bh[3][0], a3); a3 = mfma16h(ah1, bh[3][1], a3);
      if (lane < 16) {
        *(f4*)&glds[w][0][l15][0] = a0;
        *(f4*)&glds[w][1][l15][0] = a1;
        *(f4*)&glds[w][2][l15][0] = a2;
        *(f4*)&glds[w][3][l15][0] = a3;
      }
      // intra-wave write->read: compiler lgkmcnt, no barrier (R2-proven)
      float gi = glds[w][0][l15][q];
      float gf = glds[w][1][l15][q];
      float gt = glds[w][2][l15][q];
      float go = glds[w][3][l15][q];
      cc = sigm(gf)*cc + sigm(gi)*tanhf_(gt);
      float hh = sigm(go)*tanhf_(cc);
      hb[p1][q][w*16 + l15] = (_Float16)hh;
      const int to = dir ? (SEQ-1 - t) : t;
      lout[((size_t)to*4 + q)*128 + dir*64 + w*16 + l15] = hh;
      barrier_lds_only();           // single barrier: publish h
    };

    for (int t0 = 0; t0 < SEQ; t0 += 4) {
      step(t0+0, gp0); if (t0+4 < SEQ) loadG(t0+4, gp0);
      step(t0+1, gp1); if (t0+5 < SEQ) loadG(t0+5, gp1);
      step(t0+2, gp2); if (t0+6 < SEQ) loadG(t0+6, gp2);
      step(t0+3, gp3); if (t0+7 < SEQ) loadG(t0+7, gp3);
    }
    return;
  }

  // ---------------- mamba riders ----------------
  int rb = blockIdx.x - 2;

  if (stage == 1) {       // conv4 + silu: xi [NM,256] -> xc [NM,256]
    int idx = rb*256 + tid;          // < NM*256
    int d = idx & 255, m2 = idx >> 8;
    int t = m2 >> 2, b = m2 & 3;
    float s = rbias[d];
    #pragma unroll
    for (int k = 0; k < 4; ++k) {
      int tt = t - 3 + k;
      if (tt >= 0) s += rA[(size_t)((tt*4 + b) << 8) + d] * rW[d*4 + k];
    }
    rout[idx] = s * sigm(s);
    return;
  }

  if (stage == 3) {       // selective scan, wave per (b,d)
    const int wid = rb*4 + (tid >> 6);
    const int lane = tid & 63;
    const int b = wid >> 8, d = wid & 255;
    const float Av = -__expf(mAlog[d*64 + lane]);
    const float* pB  = mdbc + (size_t)b*136 + 8 + lane;
    const float* pC  = mdbc + (size_t)b*136 + 72 + lane;
    const float* pdt = mdtb + (size_t)b*256 + d;
    const float* px  = mxc  + (size_t)b*256 + d;
    float* py = mys + (size_t)b*256 + d;
    float h = 0.f;
    float Bv = pB[0], Cv = pC[0], dtv = pdt[0], xv = px[0];
    #pragma unroll 2
    for (int t = 0; t < SEQ; ++t) {
      float Bn = 0.f, Cn = 0.f, dtn = 0.f, xn = 0.f;
      if (t + 1 < SEQ) {
        size_t od = (size_t)(t+1) * 544;
        size_t ox = (size_t)(t+1) * 1024;
        Bn = pB[od]; Cn = pC[od]; dtn = pdt[ox]; xn = px[ox];
      }
      float a = __expf(dtv * Av);
      h = a*h + (dtv*xv)*Bv;
      float p = h * Cv;
      #pragma unroll
      for (int mm = 1; mm < 64; mm <<= 1) p += __shfl_xor(p, mm, 64);
      if (lane == 0) py[(size_t)t * 1024] = p;
      Bv = Bn; Cv = Cn; dtv = dtn; xv = xn;
    }
    return;
  }

  // stage 0 / 2: 64x64-tile gemm rider (256 threads).
  // gO = gA @ gW^T (+gB), gW row stride = K.  For stage 0, rider blocks
  // rb >= 512 are the z-gemm (weights dtW, bias dtB, out dtout) — same
  // N=256/K=23 shape as the xi-gemm.
  const float* gW = rW; const float* gB = rbias; float* gO = rout;
  if (stage == 0 && rb >= 512) { rb -= 512; gW = dtW; gB = dtB; gO = dtout; }
  const int ntiles = (N + 63) >> 6;
  const int nt = rb % ntiles, mt = rb / ntiles;
  const int n0 = nt * 64, m0 = mt * 64;
  const int tn = tid & 15, tm = tid >> 4;
  const int srow = tid >> 2, sk = (tid & 3) * 4;
  float acc[4][4] = {};
  for (int k0 = 0; k0 < K; k0 += 16) {
    #pragma unroll
    for (int qq = 0; qq < 4; ++qq) {
      int k = k0 + sk + qq;
      As[srow][sk + qq] = (k < K) ? rA[(size_t)(m0 + srow) * lda + k] : 0.f;
      Ws[srow][sk + qq] = (n0 + srow < N && k < K) ? gW[(size_t)(n0 + srow) * K + k] : 0.f;
    }
    __syncthreads();
    #pragma unroll
    for (int k = 0; k < 16; ++k) {
      float a[4], w[4];
      #pragma unroll
      for (int i = 0; i < 4; ++i) a[i] = As[tm*4+i][k];
      #pragma unroll
      for (int j = 0; j < 4; ++j) w[j] = Ws[tn*4+j][k];
      #pragma unroll
      for (int i = 0; i < 4; ++i)
        #pragma unroll
        for (int j = 0; j < 4; ++j) acc[i][j] += a[i]*w[j];
    }
    __syncthreads();
  }
  #pragma unroll
  for (int i = 0; i < 4; ++i) {
    #pragma unroll
    for (int j = 0; j < 4; ++j) {
      int m2 = m0 + tm*4 + i, n = n0 + tn*4 + j;
      if (n >= N) continue;
      float v = acc[i][j] + (gB ? gB[n] : 0.f);
      gO[(size_t)m2 * ldo + n] = v;
      if (stage == 2 && nt == 0 && n < 8) dtl[tm*4+i][n] = v;
    }
  }
  if (stage == 2 && nt == 0) {
    // dt = softplus(dbc[:, :8] @ dtW^T + dtB) for this block's 64 rows
    __syncthreads();
    for (int idx = tid; idx < 64*256; idx += 256) {
      int ml = idx >> 8, d = idx & 255;
      float s = dtB[d];
      #pragma unroll
      for (int r = 0; r < 8; ++r) s += dtl[ml][r] * dtW[d*8 + r];
      s = (s > 15.f) ? s : __logf(1.f + __expf(s));
      dtout[(size_t)(m0 + ml)*256 + d] = s;
    }
  }
}

// final LayerNorm(concat) -> gate -> mix.  One wave per (t,b).
__global__ __launch_bounds__(256) void combine_k(
    const float* __restrict__ lstm, const float* __restrict__ mam,
    const float* __restrict__ lnw, const float* __restrict__ lnb,
    const float* __restrict__ gW, const float* __restrict__ gb,
    float* __restrict__ out)
{
  const int pair = blockIdx.x * 4 + (threadIdx.x >> 6);
  const int lane = threadIdx.x & 63;
  const float2 lv = *(const float2*)(lstm + (size_t)pair*128 + lane*2);
  const float2 mv = *(const float2*)(mam  + (size_t)pair*128 + lane*2);
  float s  = lv.x + lv.y + mv.x + mv.y;
  float sq = lv.x*lv.x + lv.y*lv.y + mv.x*mv.x + mv.y*mv.y;
  #pragma unroll
  for (int mm = 1; mm < 64; mm <<= 1) { s += __shfl_xor(s, mm, 64); sq += __shfl_xor(sq, mm, 64); }
  const float mean = s * (1.f/256.f);
  const float var  = sq * (1.f/256.f) - mean*mean;
  const float inv  = rsqrtf(var + 1e-5f);
  const int c0 = lane*2, c2 = 128 + lane*2;
  float n0 = (lv.x-mean)*inv*lnw[c0]   + lnb[c0];
  float n1 = (lv.y-mean)*inv*lnw[c0+1] + lnb[c0+1];
  float n2 = (mv.x-mean)*inv*lnw[c2]   + lnb[c2];
  float n3 = (mv.y-mean)*inv*lnw[c2+1] + lnb[c2+1];
  float dot = n0*gW[c0] + n1*gW[c0+1] + n2*gW[c2] + n3*gW[c2+1];
  #pragma unroll
  for (int mm = 1; mm < 64; mm <<= 1) dot += __shfl_xor(dot, mm, 64);
  const float gate = sigm(dot + gb[0]);
  float2 o;
  o.x = gate*lv.x + (1.f-gate)*mv.x;
  o.y = gate*lv.y + (1.f-gate)*mv.y;
  *(float2*)(out + (size_t)pair*128 + lane*2) = o;
}

extern "C" void kernel_launch(void* const* d_in, const int* in_sizes, int n_in,
                              void* d_out, int out_size, void* d_ws, size_t ws_size,
                              hipStream_t stream)
{
  const float* x       = (const float*)d_in[0];
  const float* Wih0    = (const float*)d_in[1];
  const float* WihR    = (const float*)d_in[2];
  const float* Whh     = (const float*)d_in[3];
  const float* bih     = (const float*)d_in[4];
  const float* bhh     = (const float*)d_in[5];
  const float* mprojW  = (const float*)d_in[6];
  const float* mprojB  = (const float*)d_in[7];
  const float* inprojW = (const float*)d_in[8];
  const float* convw   = (const float*)d_in[9];
  const float* convb   = (const float*)d_in[10];
  const float* xprojW  = (const float*)d_in[11];
  const float* dtW     = (const float*)d_in[12];
  const float* dtB     = (const float*)d_in[13];
  const float* Alog    = (const float*)d_in[14];
  const float* Dskip   = (const float*)d_in[15];
  const float* outprojW= (const float*)d_in[16];
  const float* lnw     = (const float*)d_in[17];
  const float* lnb     = (const float*)d_in[18];
  const float* gWt     = (const float*)d_in[19];
  const float* gb      = (const float*)d_in[20];

  float* WS = (float*)d_ws;
  const size_t M1 = 1048576;
  // Workspace map (floats).  Base high water = 1 + 13.25 M1 (R8-proven);
  // with the z-rider we need a fresh 2M1 region past ysb -> 16.25M1 total
  // (65 MB).  Deterministic ws_size check keeps graph capture safe.
  float* mamba_out = WS;                    // [NM,128]
  float* P     = WS + M1;
  float* G     = P;                         // [2][SEQ][256][4] = 4M1 (lstm)
  float* lstmA = P + 4*M1;                  // [NM,128]
  float* lstmB = P + 5*M1;                  // [NM,128]
  float* xi    = P + 6*M1;                  // [NM,256] (F0 out, F1 in)
  float* dtb   = P + 6*M1;                  // alias: [NM,256] (F2 out, F3 in)
  float* xc    = P + 8*M1;                  // [NM,256] (F1 out; F2, tail in)
  float* dbc   = P + 10*M1;                 // [NM,136] (F2 out, F3 in)
  float* wc    = P + 10*M1 + (size_t)NM*136;// [512][23]
  float* bvec  = wc + 512*23;               // [512]
  float* ysb   = P + 11*M1 + M1/4;          // [NM,256] (F3 out, tail in)
  const bool zOK = ws_size >= 65ull*1048576; // room for dedicated z region?
  float* zbuf  = zOK ? (P + 13*M1 + M1/4)   // [NM,256], written in l=0 launch
                     : (P + 6*M1);          // fallback: alias, tail z-gemm
  float* outp  = (float*)d_out;

  dim3 blk(256);

  // pre: fold mproj into in_proj  (W' = inprojW@mprojW, b' = inprojW@mprojB)
  wcomb_k<<<48, blk, 0, stream>>>(inprojW, mprojW, mprojB, wc, bvec);

  // ---- LSTM layers with mamba stages riding the scan launches ----
  const float* lin = x;
  float* louts[4] = {lstmA, lstmB, lstmA, lstmB};
  for (int l = 0; l < 4; ++l) {
    const float* w0; const float* w1; int K;
    if (l == 0) { w0 = Wih0; w1 = Wih0 + 256*23; K = 23; }
    else {
      w0 = WihR + (size_t)((l-1)*2 + 0)*256*128;
      w1 = WihR + (size_t)((l-1)*2 + 1)*256*128;
      K = 128;
    }
    gemm_k<<<dim3(8,128), blk, 0, stream>>>(lin, K, w0, w1, 256,
        bih + (l*2+0)*256, bhh + (l*2+0)*256,
        bih + (l*2+1)*256, bhh + (l*2+1)*256,
        G, NM, 512, K, 2);
    const float* Wl = Whh + (size_t)l*2*256*64;
    if (l == 0) {        // rider: xi = x @ W'[0:256]^T + b' (512 blocks)
                         //  + optional z = x @ W'[256:512]^T (512 more)
      fused_k<<<2 + (zOK ? 1024 : 512), blk, 0, stream>>>(0, G, Wl, louts[l],
          x, 23, wc, bvec, xi, 256, 256, 23,
          zOK ? (wc + 256*23) : nullptr, zOK ? (bvec + 256) : nullptr,
          zOK ? zbuf : nullptr, nullptr, nullptr, nullptr, nullptr, nullptr);
    } else if (l == 1) { // rider: conv+silu (NM*256 / 256 blocks)
      fused_k<<<2 + 8192, blk, 0, stream>>>(1, G, Wl, louts[l],
          xi, 0, convw, convb, xc, 0, 0, 0,
          nullptr, nullptr, nullptr, nullptr, nullptr, nullptr, nullptr, nullptr);
    } else if (l == 2) { // rider: xproj (3 x 128 tiles) + fused dt
      fused_k<<<2 + 384, blk, 0, stream>>>(2, G, Wl, louts[l],
          xc, 256, xprojW, nullptr, dbc, 136, 136, 256,
          dtW, dtB, dtb, nullptr, nullptr, nullptr, nullptr, nullptr);
    } else {             // rider: mamba selective scan (256 blocks x 4 waves)
      fused_k<<<2 + 256, blk, 0, stream>>>(3, G, Wl, louts[l],
          nullptr, 0, nullptr, nullptr, nullptr, 0, 0, 0,
          nullptr, nullptr, nullptr, dbc, dtb, xc, Alog, ysb);
    }
    lin = louts[l];
  }

  // ---- tail: [z-gemm if not ridden], fused ycomb+out_proj, gate+mix ----
  if (!zOK) {
    gemm_k<<<dim3(4,128), blk, 0, stream>>>(x, 23, wc + 256*23, nullptr, 256,
        bvec + 256, nullptr, nullptr, nullptr, zbuf, NM, 256, 23, 0);
  }
  moutproj_k<<<dim3(2,128), blk, 0, stream>>>(zbuf, ysb, xc, Dskip,
      outprojW, mamba_out);
  combine_k<<<2048, blk, 0, stream>>>(lstmB, mamba_out, lnw, lnb, gWt, gb, outp);
}

// Round 14
// 4576.385 us; speedup vs baseline: 1.3849x; 1.0050x over previous
//
#include <hip/hip_runtime.h>

#define SEQ   2048
#define NM    8192        // SEQ*BATCH

typedef __attribute__((ext_vector_type(4))) float f4;
typedef _Float16 f16x8 __attribute__((ext_vector_type(8)));

__device__ __forceinline__ float frcp(float x){ return __builtin_amdgcn_rcpf(x); }
__device__ __forceinline__ float sigm(float x){ return frcp(1.f + __expf(-x)); }
__device__ __forceinline__ float tanhf_(float x){ return 1.f - 2.f*frcp(__expf(2.f*x) + 1.f); }
__device__ __forceinline__ f4 mfma16h(f16x8 a, f16x8 b, f4 c){
  return __builtin_amdgcn_mfma_f32_16x16x32_f16(a, b, c, 0, 0, 0);
}
// LDS-only barrier: scan h/glds coherence needs lgkmcnt(0) only; G prefetch
// global loads stay in flight across the barrier.
__device__ __forceinline__ void barrier_lds_only(){
  asm volatile("s_waitcnt lgkmcnt(0)\n\ts_barrier" ::: "memory");
}

// ---------------------------------------------------------------------------
// Generic tiled GEMM (256 thr): out = A[M,K] @ W[N,K]^T (+bias), epilogues.
// mode 0: plain   mode 2: LSTM-G store [dir][t][j][b], time-reversed for dir1.
// R14: LDS staged TRANSPOSED ([k][row], stride 68 words = 272B, 16B-aligned,
// 4 banks mod 32 -> <=2-way) so the microkernel fetches a[4]/w[4] as single
// ds_read_b128 (was 8 scalar b32/k — LDS-issue-bound).  Same k order, same
// products -> bit-identical accumulation.
// ---------------------------------------------------------------------------
__global__ __launch_bounds__(256) void gemm_k(
    const float* __restrict__ A, int lda,
    const float* __restrict__ W0, const float* __restrict__ W1, int Nhalf,
    const float* __restrict__ b0a, const float* __restrict__ b0b,
    const float* __restrict__ b1a, const float* __restrict__ b1b,
    float* __restrict__ out, int M, int N, int K, int mode)
{
  __shared__ alignas(16) float As[16][68];   // [k][row]
  __shared__ alignas(16) float Ws[16][68];   // [k][col]
  const int tid = threadIdx.x;
  const int tn = tid & 15, tm = tid >> 4;
  const int n0 = blockIdx.x * 64, m0 = blockIdx.y * 64;
  const int srow = tid >> 2, sk = (tid & 3) * 4;
  float acc[4][4] = {};
  for (int k0 = 0; k0 < K; k0 += 16) {
    const int am = m0 + srow;
    #pragma unroll
    for (int q = 0; q < 4; ++q) {
      int k = k0 + sk + q;
      As[sk + q][srow] = (k < K) ? A[(size_t)am * lda + k] : 0.f;
    }
    const int wn = n0 + srow;
    const float* Wp = W0; int nn = wn;
    if (W1 != nullptr && wn >= Nhalf) { Wp = W1; nn = wn - Nhalf; }
    #pragma unroll
    for (int q = 0; q < 4; ++q) {
      int k = k0 + sk + q;
      Ws[sk + q][srow] = (wn < N && k < K) ? Wp[(size_t)nn * K + k] : 0.f;
    }
    __syncthreads();
    #pragma unroll
    for (int k = 0; k < 16; ++k) {
      f4 a = *(const f4*)&As[k][tm*4];
      f4 w = *(const f4*)&Ws[k][tn*4];
      #pragma unroll
      for (int i = 0; i < 4; ++i)
        #pragma unroll
        for (int j = 0; j < 4; ++j) acc[i][j] += a[i]*w[j];
    }
    __syncthreads();
  }
  #pragma unroll
  for (int i = 0; i < 4; ++i) {
    #pragma unroll
    for (int j = 0; j < 4; ++j) {
      int m = m0 + tm*4 + i, n = n0 + tn*4 + j;
      if (n >= N) continue;
      float bias = 0.f;
      if (n < Nhalf) { if (b0a) bias += b0a[n]; if (b0b) bias += b0b[n]; }
      else { if (b1a) bias += b1a[n - Nhalf]; if (b1b) bias += b1b[n - Nhalf]; }
      float v = acc[i][j] + bias;
      if (mode == 2) {
        int dd = n >> 8, jj = n & 255, t = m >> 2, b = m & 3;
        int tq = dd ? (SEQ - 1 - t) : t;
        out[((size_t)(dd*SEQ + tq) * 256 + jj) * 4 + b] = v;
      } else {
        out[(size_t)m * N + n] = v;
      }
    }
  }
}

// W' = inprojW @ mprojW (512x23, row stride 23), b' = inprojW @ mprojB (512)
__global__ __launch_bounds__(256) void wcomb_k(
    const float* __restrict__ inprojW, const float* __restrict__ mprojW,
    const float* __restrict__ mprojB, float* __restrict__ wc,
    float* __restrict__ bvec)
{
  int idx = blockIdx.x * 256 + threadIdx.x;
  if (idx >= 512 * 24) return;
  int n = idx / 24, c = idx % 24;
  const float* wi = inprojW + (size_t)n * 128;
  float s = 0.f;
  if (c < 23) {
    for (int k = 0; k < 128; ++k) s += wi[k] * mprojW[k*23 + c];
    wc[n*23 + c] = s;
  } else {
    for (int k = 0; k < 128; ++k) s += wi[k] * mprojB[k];
    bvec[n] = s;
  }
}

// out = yc @ Wp[128,256]^T with yc computed inline: yc = (ys + xc*D)*silu(z).
// Same transposed-staging vectorized microkernel as gemm_k.
__global__ __launch_bounds__(256) void moutproj_k(
    const float* __restrict__ z, const float* __restrict__ ys,
    const float* __restrict__ xc, const float* __restrict__ Dsk,
    const float* __restrict__ Wp, float* __restrict__ out)
{
  __shared__ alignas(16) float As[16][68];
  __shared__ alignas(16) float Ws[16][68];
  const int tid = threadIdx.x;
  const int tn = tid & 15, tm = tid >> 4;
  const int n0 = blockIdx.x * 64, m0 = blockIdx.y * 64;
  const int srow = tid >> 2, sk = (tid & 3) * 4;
  float acc[4][4] = {};
  for (int k0 = 0; k0 < 256; k0 += 16) {
    #pragma unroll
    for (int q = 0; q < 4; ++q) {
      int k = k0 + sk + q;
      size_t idx = (size_t)(m0 + srow) * 256 + k;
      float zz = z[idx];
      As[sk + q][srow] = (ys[idx] + xc[idx]*Dsk[k]) * zz * sigm(zz);
      Ws[sk + q][srow] = Wp[(size_t)(n0 + srow) * 256 + k];
    }
    __syncthreads();
    #pragma unroll
    for (int k = 0; k < 16; ++k) {
      f4 a = *(const f4*)&As[k][tm*4];
      f4 w = *(const f4*)&Ws[k][tn*4];
      #pragma unroll
      for (int i = 0; i < 4; ++i)
        #pragma unroll
        for (int j = 0; j < 4; ++j) acc[i][j] += a[i]*w[j];
    }
    __syncthreads();
  }
  #pragma unroll
  for (int i = 0; i < 4; ++i)
    #pragma unroll
    for (int j = 0; j < 4; ++j)
      out[(size_t)(m0 + tm*4 + i) * 128 + n0 + tn*4 + j] = acc[i][j];
}

// ---------------------------------------------------------------------------
// FUSED launch (256 thr): blocks 0-1 = LSTM scan (one dir each, 4 waves —
// the R9 structure, proven best); blocks 2+ = one mamba pipeline stage.
// SCAN: wave w owns gate tiles {w, w+4, w+8, w+12}; single-pass f16 MFMA
// (8 MFMAs/wave, 2-deep chains); intra-wave glds gate redistribution;
// activations 1 value/lane on all 64 lanes; ONE lgkm barrier per step.
// Riders: stage 0 xi-gemm (+ z-gemm blocks rb>=512 when workspace allows);
// 1 conv+silu; 2 xproj+dt; 3 selective scan.  (Riders are hidden under the
// scan — kept in the R13-proven scalar form.)
// ---------------------------------------------------------------------------
#define HROW 72   // padded row stride (f16)
__global__ __launch_bounds__(256, 1) void fused_k(
    int stage,
    const float* __restrict__ G,    // [2][SEQ][256][4]
    const float* __restrict__ Whh,  // [2][256][64] (layer base)
    float* __restrict__ lout,       // [SEQ][4][128]
    const float* __restrict__ rA, int lda,
    const float* __restrict__ rW, const float* __restrict__ rbias,
    float* __restrict__ rout, int ldo, int N, int K,
    const float* __restrict__ dtW, const float* __restrict__ dtB,
    float* __restrict__ dtout,
    const float* __restrict__ mdbc, const float* __restrict__ mdtb,
    const float* __restrict__ mxc, const float* __restrict__ mAlog,
    float* __restrict__ mys)
{
  __shared__ _Float16 hb[2][16][HROW];    // scan: [buf][m=batch][k=col]
  __shared__ float glds[4][4][16][4];     // scan: [wave][gate][col][batch]
  __shared__ float As[64][17];            // gemm rider
  __shared__ float Ws[64][17];            // gemm rider
  __shared__ float dtl[64][8];            // stage-2 dt fusion

  const int tid = threadIdx.x;

  if (blockIdx.x < 2) {
    // ---------------- LSTM scan ----------------
    const int dir = blockIdx.x;
    const int w = tid >> 6, lane = tid & 63;   // w in 0..3
    const int l15 = lane & 15, q = lane >> 4;

    for (int i = tid; i < 2*16*HROW; i += 256) ((_Float16*)hb)[i] = (_Float16)0.f;

    const float* Gd = G + (size_t)dir * SEQ * 1024;
    const float* Wd = Whh + dir * 256 * 64;

    // B fragments: wave w owns gate tiles {4g+w}, g=0..3 (gate i,f,g,o)
    f16x8 bh[4][2];
    #pragma unroll
    for (int g = 0; g < 4; ++g) {
      const int j = (g*4 + w)*16 + l15;
      #pragma unroll
      for (int kt = 0; kt < 2; ++kt) {
        const float* src = Wd + j*64 + kt*32 + q*8;
        #pragma unroll
        for (int e = 0; e < 8; ++e) bh[g][kt][e] = (_Float16)src[e];
      }
    }

    float cc = 0.f;                 // cell state: lane = (batch q, col 16w+l15)
    f4 gp0[4], gp1[4], gp2[4], gp3[4];

    auto loadG = [&](int t, f4* gv) {
      #pragma unroll
      for (int g = 0; g < 4; ++g) {
        const int j = (g*4 + w)*16 + l15;
        gv[g] = *(const f4*)(Gd + ((size_t)t * 256 + j) * 4);
      }
    };
    loadG(0, gp0); loadG(1, gp1); loadG(2, gp2); loadG(3, gp3);
    __syncthreads();

    auto step = [&](int t, f4* gv) {
      const int p0 = t & 1, p1 = p0 ^ 1;
      f16x8 ah0 = *(const f16x8*)&hb[p0][l15][q*8];
      f16x8 ah1 = *(const f16x8*)&hb[p0][l15][q*8 + 32];
      f4 a0 = gv[0], a1 = gv[1], a2 = gv[2], a3 = gv[3];
      a0 = mfma16h(ah0, bh[0][0], a0); a0 = mfma16h(ah1, bh[0][1], a0);
      a1 = mfma16h(ah0, bh[1][0], a1); a1 = mfma16h(ah1, bh[1][1], a1);
      a2 = mfma16h(ah0, bh[2][0], a2); a2 = mfma16h(ah1, bh[2][1], a2);
      a3 = mfma16h(ah0, bh[3][0], a3); a3 = mfma16h(ah1, bh[3][1], a3);
      if (lane < 16) {
        *(f4*)&glds[w][0][l15][0] = a0;
        *(f4*)&glds[w][1][l15][0] = a1;
        *(f4*)&glds[w][2][l15][0] = a2;
        *(f4*)&glds[w][3][l15][0] = a3;
      }
      // intra-wave write->read: compiler lgkmcnt, no barrier (R2-proven)
      float gi = glds[w][0][l15][q];
      float gf = glds[w][1][l15][q];
      float gt = glds[w][2][l15][q];
      float go = glds[w][3][l15][q];
      cc = sigm(gf)*cc + sigm(gi)*tanhf_(gt);
      float hh = sigm(go)*tanhf_(cc);
      hb[p1][q][w*16 + l15] = (_Float16)hh;
      const int to = dir ? (SEQ-1 - t) : t;
      lout[((size_t)to*4 + q)*128 + dir*64 + w*16 + l15] = hh;
      barrier_lds_only();           // single barrier: publish h
    };

    for (int t0 = 0; t0 < SEQ; t0 += 4) {
      step(t0+0, gp0); if (t0+4 < SEQ) loadG(t0+4, gp0);
      step(t0+1, gp1); if (t0+5 < SEQ) loadG(t0+5, gp1);
      step(t0+2, gp2); if (t0+6 < SEQ) loadG(t0+6, gp2);
      step(t0+3, gp3); if (t0+7 < SEQ) loadG(t0+7, gp3);
    }
    return;
  }

  // ---------------- mamba riders ----------------
  int rb = blockIdx.x - 2;

  if (stage == 1) {       // conv4 + silu: xi [NM,256] -> xc [NM,256]
    int idx = rb*256 + tid;          // < NM*256
    int d = idx & 255, m2 = idx >> 8;
    int t = m2 >> 2, b = m2 & 3;
    float s = rbias[d];
    #pragma unroll
    for (int k = 0; k < 4; ++k) {
      int tt = t - 3 + k;
      if (tt >= 0) s += rA[(size_t)((tt*4 + b) << 8) + d] * rW[d*4 + k];
    }
    rout[idx] = s * sigm(s);
    return;
  }

  if (stage == 3) {       // selective scan, wave per (b,d)
    const int wid = rb*4 + (tid >> 6);
    const int lane = tid & 63;
    const int b = wid >> 8, d = wid & 255;
    const float Av = -__expf(mAlog[d*64 + lane]);
    const float* pB  = mdbc + (size_t)b*136 + 8 + lane;
    const float* pC  = mdbc + (size_t)b*136 + 72 + lane;
    const float* pdt = mdtb + (size_t)b*256 + d;
    const float* px  = mxc  + (size_t)b*256 + d;
    float* py = mys + (size_t)b*256 + d;
    float h = 0.f;
    float Bv = pB[0], Cv = pC[0], dtv = pdt[0], xv = px[0];
    #pragma unroll 2
    for (int t = 0; t < SEQ; ++t) {
      float Bn = 0.f, Cn = 0.f, dtn = 0.f, xn = 0.f;
      if (t + 1 < SEQ) {
        size_t od = (size_t)(t+1) * 544;
        size_t ox = (size_t)(t+1) * 1024;
        Bn = pB[od]; Cn = pC[od]; dtn = pdt[ox]; xn = px[ox];
      }
      float a = __expf(dtv * Av);
      h = a*h + (dtv*xv)*Bv;
      float p = h * Cv;
      #pragma unroll
      for (int mm = 1; mm < 64; mm <<= 1) p += __shfl_xor(p, mm, 64);
      if (lane == 0) py[(size_t)t * 1024] = p;
      Bv = Bn; Cv = Cn; dtv = dtn; xv = xn;
    }
    return;
  }

  // stage 0 / 2: 64x64-tile gemm rider (256 threads).
  // gO = gA @ gW^T (+gB), gW row stride = K.  For stage 0, rider blocks
  // rb >= 512 are the z-gemm (weights dtW, bias dtB, out dtout) — same
  // N=256/K=23 shape as the xi-gemm.
  const float* gW = rW; const float* gB = rbias; float* gO = rout;
  if (stage == 0 && rb >= 512) { rb -= 512; gW = dtW; gB = dtB; gO = dtout; }
  const int ntiles = (N + 63) >> 6;
  const int nt = rb % ntiles, mt = rb / ntiles;
  const int n0 = nt * 64, m0 = mt * 64;
  const int tn = tid & 15, tm = tid >> 4;
  const int srow = tid >> 2, sk = (tid & 3) * 4;
  float acc[4][4] = {};
  for (int k0 = 0; k0 < K; k0 += 16) {
    #pragma unroll
    for (int qq = 0; qq < 4; ++qq) {
      int k = k0 + sk + qq;
      As[srow][sk + qq] = (k < K) ? rA[(size_t)(m0 + srow) * lda + k] : 0.f;
      Ws[srow][sk + qq] = (n0 + srow < N && k < K) ? gW[(size_t)(n0 + srow) * K + k] : 0.f;
    }
    __syncthreads();
    #pragma unroll
    for (int k = 0; k < 16; ++k) {
      float a[4], w[4];
      #pragma unroll
      for (int i = 0; i < 4; ++i) a[i] = As[tm*4+i][k];
      #pragma unroll
      for (int j = 0; j < 4; ++j) w[j] = Ws[tn*4+j][k];
      #pragma unroll
      for (int i = 0; i < 4; ++i)
        #pragma unroll
        for (int j = 0; j < 4; ++j) acc[i][j] += a[i]*w[j];
    }
    __syncthreads();
  }
  #pragma unroll
  for (int i = 0; i < 4; ++i) {
    #pragma unroll
    for (int j = 0; j < 4; ++j) {
      int m2 = m0 + tm*4 + i, n = n0 + tn*4 + j;
      if (n >= N) continue;
      float v = acc[i][j] + (gB ? gB[n] : 0.f);
      gO[(size_t)m2 * ldo + n] = v;
      if (stage == 2 && nt == 0 && n < 8) dtl[tm*4+i][n] = v;
    }
  }
  if (stage == 2 && nt == 0) {
    // dt = softplus(dbc[:, :8] @ dtW^T + dtB) for this block's 64 rows
    __syncthreads();
    for (int idx = tid; idx < 64*256; idx += 256) {
      int ml = idx >> 8, d = idx & 255;
      float s = dtB[d];
      #pragma unroll
      for (int r = 0; r < 8; ++r) s += dtl[ml][r] * dtW[d*8 + r];
      s = (s > 15.f) ? s : __logf(1.f + __expf(s));
      dtout[(size_t)(m0 + ml)*256 + d] = s;
    }
  }
}

// final LayerNorm(concat) -> gate -> mix.  One wave per (t,b).
__global__ __launch_bounds__(256) void combine_k(
    const float* __restrict__ lstm, const float* __restrict__ mam,
    const float* __restrict__ lnw, const float* __restrict__ lnb,
    const float* __restrict__ gW, const float* __restrict__ gb,
    float* __restrict__ out)
{
  const int pair = blockIdx.x * 4 + (threadIdx.x >> 6);
  const int lane = threadIdx.x & 63;
  const float2 lv = *(const float2*)(lstm + (size_t)pair*128 + lane*2);
  const float2 mv = *(const float2*)(mam  + (size_t)pair*128 + lane*2);
  float s  = lv.x + lv.y + mv.x + mv.y;
  float sq = lv.x*lv.x + lv.y*lv.y + mv.x*mv.x + mv.y*mv.y;
  #pragma unroll
  for (int mm = 1; mm < 64; mm <<= 1) { s += __shfl_xor(s, mm, 64); sq += __shfl_xor(sq, mm, 64); }
  const float mean = s * (1.f/256.f);
  const float var  = sq * (1.f/256.f) - mean*mean;
  const float inv  = rsqrtf(var + 1e-5f);
  const int c0 = lane*2, c2 = 128 + lane*2;
  float n0 = (lv.x-mean)*inv*lnw[c0]   + lnb[c0];
  float n1 = (lv.y-mean)*inv*lnw[c0+1] + lnb[c0+1];
  float n2 = (mv.x-mean)*inv*lnw[c2]   + lnb[c2];
  float n3 = (mv.y-mean)*inv*lnw[c2+1] + lnb[c2+1];
  float dot = n0*gW[c0] + n1*gW[c0+1] + n2*gW[c2] + n3*gW[c2+1];
  #pragma unroll
  for (int mm = 1; mm < 64; mm <<= 1) dot += __shfl_xor(dot, mm, 64);
  const float gate = sigm(dot + gb[0]);
  float2 o;
  o.x = gate*lv.x + (1.f-gate)*mv.x;
  o.y = gate*lv.y + (1.f-gate)*mv.y;
  *(float2*)(out + (size_t)pair*128 + lane*2) = o;
}

extern "C" void kernel_launch(void* const* d_in, const int* in_sizes, int n_in,
                              void* d_out, int out_size, void* d_ws, size_t ws_size,
                              hipStream_t stream)
{
  const float* x       = (const float*)d_in[0];
  const float* Wih0    = (const float*)d_in[1];
  const float* WihR    = (const float*)d_in[2];
  const float* Whh     = (const float*)d_in[3];
  const float* bih     = (const float*)d_in[4];
  const float* bhh     = (const float*)d_in[5];
  const float* mprojW  = (const float*)d_in[6];
  const float* mprojB  = (const float*)d_in[7];
  const float* inprojW = (const float*)d_in[8];
  const float* convw   = (const float*)d_in[9];
  const float* convb   = (const float*)d_in[10];
  const float* xprojW  = (const float*)d_in[11];
  const float* dtW     = (const float*)d_in[12];
  const float* dtB     = (const float*)d_in[13];
  const float* Alog    = (const float*)d_in[14];
  const float* Dskip   = (const float*)d_in[15];
  const float* outprojW= (const float*)d_in[16];
  const float* lnw     = (const float*)d_in[17];
  const float* lnb     = (const float*)d_in[18];
  const float* gWt     = (const float*)d_in[19];
  const float* gb      = (const float*)d_in[20];

  float* WS = (float*)d_ws;
  const size_t M1 = 1048576;
  // Workspace map (floats).  Base high water = 1 + 13.25 M1 (R8-proven);
  // with the z-rider we need a fresh 2M1 region past ysb -> 16.25M1 total
  // (65 MB).  Deterministic ws_size check keeps graph capture safe.
  float* mamba_out = WS;                    // [NM,128]
  float* P     = WS + M1;
  float* G     = P;                         // [2][SEQ][256][4] = 4M1 (lstm)
  float* lstmA = P + 4*M1;                  // [NM,128]
  float* lstmB = P + 5*M1;                  // [NM,128]
  float* xi    = P + 6*M1;                  // [NM,256] (F0 out, F1 in)
  float* dtb   = P + 6*M1;                  // alias: [NM,256] (F2 out, F3 in)
  float* xc    = P + 8*M1;                  // [NM,256] (F1 out; F2, tail in)
  float* dbc   = P + 10*M1;                 // [NM,136] (F2 out, F3 in)
  float* wc    = P + 10*M1 + (size_t)NM*136;// [512][23]
  float* bvec  = wc + 512*23;               // [512]
  float* ysb   = P + 11*M1 + M1/4;          // [NM,256] (F3 out, tail in)
  const bool zOK = ws_size >= 65ull*1048576; // room for dedicated z region?
  float* zbuf  = zOK ? (P + 13*M1 + M1/4)   // [NM,256], written in l=0 launch
                     : (P + 6*M1);          // fallback: alias, tail z-gemm
  float* outp  = (float*)d_out;

  dim3 blk(256);

  // pre: fold mproj into in_proj  (W' = inprojW@mprojW, b' = inprojW@mprojB)
  wcomb_k<<<48, blk, 0, stream>>>(inprojW, mprojW, mprojB, wc, bvec);

  // ---- LSTM layers with mamba stages riding the scan launches ----
  const float* lin = x;
  float* louts[4] = {lstmA, lstmB, lstmA, lstmB};
  for (int l = 0; l < 4; ++l) {
    const float* w0; const float* w1; int K;
    if (l == 0) { w0 = Wih0; w1 = Wih0 + 256*23; K = 23; }
    else {
      w0 = WihR + (size_t)((l-1)*2 + 0)*256*128;
      w1 = WihR + (size_t)((l-1)*2 + 1)*256*128;
      K = 128;
    }
    gemm_k<<<dim3(8,128), blk, 0, stream>>>(lin, K, w0, w1, 256,
        bih + (l*2+0)*256, bhh + (l*2+0)*256,
        bih + (l*2+1)*256, bhh + (l*2+1)*256,
        G, NM, 512, K, 2);
    const float* Wl = Whh + (size_t)l*2*256*64;
    if (l == 0) {        // rider: xi = x @ W'[0:256]^T + b' (512 blocks)
                         //  + optional z = x @ W'[256:512]^T (512 more)
      fused_k<<<2 + (zOK ? 1024 : 512), blk, 0, stream>>>(0, G, Wl, louts[l],
          x, 23, wc, bvec, xi, 256, 256, 23,
          zOK ? (wc + 256*23) : nullptr, zOK ? (bvec + 256) : nullptr,
          zOK ? zbuf : nullptr, nullptr, nullptr, nullptr, nullptr, nullptr);
    } else if (l == 1) { // rider: conv+silu (NM*256 / 256 blocks)
      fused_k<<<2 + 8192, blk, 0, stream>>>(1, G, Wl, louts[l],
          xi, 0, convw, convb, xc, 0, 0, 0,
          nullptr, nullptr, nullptr, nullptr, nullptr, nullptr, nullptr, nullptr);
    } else if (l == 2) { // rider: xproj (3 x 128 tiles) + fused dt
      fused_k<<<2 + 384, blk, 0, stream>>>(2, G, Wl, louts[l],
          xc, 256, xprojW, nullptr, dbc, 136, 136, 256,
          dtW, dtB, dtb, nullptr, nullptr, nullptr, nullptr, nullptr);
    } else {             // rider: mamba selective scan (256 blocks x 4 waves)
      fused_k<<<2 + 256, blk, 0, stream>>>(3, G, Wl, louts[l],
          nullptr, 0, nullptr, nullptr, nullptr, 0, 0, 0,
          nullptr, nullptr, nullptr, dbc, dtb, xc, Alog, ysb);
    }
    lin = louts[l];
  }

  // ---- tail: [z-gemm if not ridden], fused ycomb+out_proj, gate+mix ----
  if (!zOK) {
    gemm_k<<<dim3(4,128), blk, 0, stream>>>(x, 23, wc + 256*23, nullptr, 256,
        bvec + 256, nullptr, nullptr, nullptr, zbuf, NM, 256, 23, 0);
  }
  moutproj_k<<<dim3(2,128), blk, 0, stream>>>(zbuf, ysb, xc, Dskip,
      outprojW, mamba_out);
  combine_k<<<2048, blk, 0, stream>>>(lstmB, mamba_out, lnw, lnb, gWt, gb, outp);
}